// Round 4
// baseline (753.199 us; speedup 1.0000x reference)
//
#include <hip/hip_runtime.h>
#include <hip/hip_bf16.h>
#include <cstddef>

// Problem constants (match reference).
#define NQ 8192
#define DD 1024

typedef __attribute__((ext_vector_type(8))) short s8v;     // 8 bf16 (4 VGPR)
typedef __attribute__((ext_vector_type(8))) int i8v;       // 32 fp8 bytes (8 VGPR)
typedef __attribute__((ext_vector_type(4))) float f32x4;   // 16x16 C/D frag
typedef __attribute__((ext_vector_type(16))) float f32x16; // 32x32 C/D frag

typedef const __attribute__((address_space(1))) unsigned int* gptr_t;
typedef __attribute__((address_space(3))) unsigned int* lptr_t;

#define SCALE_1_16 0x7B7B7B7Bu  // E8M0 123 = 2^-4 in every byte

__device__ inline unsigned short f2bf(float f) {
  union { float f; unsigned u; } v; v.f = f;
  unsigned r = (v.u + 0x7FFFu + ((v.u >> 16) & 1u)) >> 16;  // RNE
  return (unsigned short)r;
}
__device__ inline float bf2f(unsigned short u) {
  union { unsigned u; float f; } v; v.u = ((unsigned)u) << 16;
  return v.f;
}

// f32 -> OCP e4m3 bits, RNE, clamp to +-448. Inputs here are well within
// range (|x| <~ 4 after the 16x pre-scale).
__device__ inline unsigned char f2e4m3(float x) {
  union { float f; unsigned u; } v; v.f = x;
  const unsigned s = (v.u >> 31) << 7;
  unsigned au = v.u & 0x7FFFFFFFu;
  if (au > 0x43E00000u) au = 0x43E00000u;  // clamp |x| to 448.0
  if (au >= 0x3C800000u) {                 // |x| >= 2^-6: e4m3 normal
    const unsigned rounded = au + 0x7FFFFu + ((au >> 20) & 1u);  // RNE @ 3 mant bits
    const unsigned e8 = ((rounded >> 23) & 0xFF) - 120u;         // -127+7
    const unsigned m8 = (rounded >> 20) & 7u;
    return (unsigned char)(s | (e8 << 3) | m8);
  } else {                                 // subnormal: round(|x| / 2^-9)
    union { unsigned u; float f; } a; a.u = au;
    const unsigned q = (unsigned)rintf(a.f * 512.0f);  // 0..8 (8 -> 2^-6 exact)
    return (unsigned char)(s | q);
  }
}

// ---------------------------------------------------------------------------
// m97-style bf16 MFMA main loop (unchanged from round 3): C(128x128) +=
// A(128xK) @ B(128xK)^T. BK=64, global_load_lds dwordx4 staging, 4 waves,
// each 64x64 via 4x4 of 16x16x32 bf16 MFMA. Used by proj_gemm and pv.
// ---------------------------------------------------------------------------
template <int KDIM, int ASTR, int BSTR>
__device__ inline void mfma_core(const unsigned short* __restrict__ A,
                                 const unsigned short* __restrict__ B,
                                 int i0, int j0, int tid,
                                 unsigned short* AsU, unsigned short* BsU,
                                 f32x4 (&acc)[4][4]) {
  const int lane = tid & 63;
  const int w = tid >> 6;
  const int wr = (w >> 1) * 64;
  const int wc = (w & 1) * 64;
  const int l16 = lane & 15;
  const int lq = lane >> 4;
  const int srow = lane >> 3;
  const int scol = (lane & 7) * 8;

  for (int kk = 0; kk < KDIM; kk += 64) {
    __syncthreads();
#pragma unroll
    for (int t = 0; t < 4; t++) {
      const int r0 = w * 32 + t * 8;
      const unsigned short* g = &A[(size_t)(i0 + r0 + srow) * ASTR + kk + scol];
      __builtin_amdgcn_global_load_lds((gptr_t)(const void*)g,
                                       (lptr_t)(void*)&AsU[r0 * 64], 16, 0, 0);
    }
#pragma unroll
    for (int t = 0; t < 4; t++) {
      const int r0 = w * 32 + t * 8;
      const unsigned short* g = &B[(size_t)(j0 + r0 + srow) * BSTR + kk + scol];
      __builtin_amdgcn_global_load_lds((gptr_t)(const void*)g,
                                       (lptr_t)(void*)&BsU[r0 * 64], 16, 0, 0);
    }
    __syncthreads();

    s8v af[4][2], bf[4][2];
#pragma unroll
    for (int t = 0; t < 4; t++)
#pragma unroll
      for (int s = 0; s < 2; s++) {
        af[t][s] = *(const s8v*)&AsU[(wr + 16 * t + l16) * 64 + s * 32 + lq * 8];
        bf[t][s] = *(const s8v*)&BsU[(wc + 16 * t + l16) * 64 + s * 32 + lq * 8];
      }
#pragma unroll
    for (int s = 0; s < 2; s++)
#pragma unroll
      for (int a = 0; a < 4; a++)
#pragma unroll
        for (int b = 0; b < 4; b++)
          acc[a][b] = __builtin_amdgcn_mfma_f32_16x16x32_bf16(
              af[a][s], bf[b][s], acc[a][b], 0, 0, 0);
  }
}

// ---------------------------------------------------------------------------
// fp32 -> bf16 elementwise.
// ---------------------------------------------------------------------------
__global__ void f32_to_bf16(const float* __restrict__ in,
                            unsigned short* __restrict__ out, int n4) {
  int i = (blockIdx.x * blockDim.x + threadIdx.x);
  if (i < n4) {
    const float4 v = *(const float4*)&in[i * 4];
    ushort4 o;
    o.x = f2bf(v.x); o.y = f2bf(v.y); o.z = f2bf(v.z); o.w = f2bf(v.w);
    *(ushort4*)&out[i * 4] = o;
  }
}

// ---------------------------------------------------------------------------
// fp32 [R][C] -> bf16 [C][R] transpose+convert (32x32 LDS tiles).
// ---------------------------------------------------------------------------
__global__ void transpose_cvt(const float* __restrict__ in,
                              unsigned short* __restrict__ out, int R, int C) {
  __shared__ float t[32][33];
  const int bx = blockIdx.x;
  const int by = blockIdx.y;
  const int x = threadIdx.x & 31;
  const int y = threadIdx.x >> 5;
#pragma unroll
  for (int i = 0; i < 32; i += 8)
    t[y + i][x] = in[(size_t)(by * 32 + y + i) * C + bx * 32 + x];
  __syncthreads();
#pragma unroll
  for (int i = 0; i < 32; i += 8)
    out[(size_t)(bx * 32 + y + i) * R + by * 32 + x] = f2bf(t[x][y + i]);
}

// ---------------------------------------------------------------------------
// Projection GEMM: C[m][n] = sum_k A[m][k] * BT[n][k], bf16 in, K=1024.
// FP8OUT=false: write bf16 (row stride NST).  FP8OUT=true: write e4m3 of
// 16*value (pre-scaled for the MX qk pass), row stride NST.
// ---------------------------------------------------------------------------
template <int NST, bool FP8OUT>
__global__ __launch_bounds__(256, 2)
void proj_gemm(const unsigned short* __restrict__ A,
               const unsigned short* __restrict__ BT,
               void* __restrict__ Cout) {
  __shared__ __align__(16) unsigned short As[128 * 64];
  __shared__ __align__(16) unsigned short Bs[128 * 64];
  const int tid = threadIdx.x;
  const int m0 = blockIdx.y * 128;
  const int n0 = blockIdx.x * 128;

  f32x4 acc[4][4];
#pragma unroll
  for (int a = 0; a < 4; a++)
#pragma unroll
    for (int b = 0; b < 4; b++) acc[a][b] = (f32x4){0.f, 0.f, 0.f, 0.f};

  mfma_core<DD, DD, DD>(A, BT, m0, n0, tid, As, Bs, acc);

  const int lane = tid & 63;
  const int w = tid >> 6;
  const int wr = (w >> 1) * 64, wc = (w & 1) * 64;
  const int l16 = lane & 15, lq = lane >> 4;
#pragma unroll
  for (int ti = 0; ti < 4; ti++)
#pragma unroll
    for (int r = 0; r < 4; r++) {
      const int row = m0 + wr + 16 * ti + lq * 4 + r;
#pragma unroll
      for (int tj = 0; tj < 4; tj++) {
        const int col = n0 + wc + 16 * tj + l16;
        if (FP8OUT) {
          ((unsigned char*)Cout)[(size_t)row * NST + col] =
              f2e4m3(acc[ti][tj][r] * 16.f);
        } else {
          ((unsigned short*)Cout)[(size_t)row * NST + col] = f2bf(acc[ti][tj][r]);
        }
      }
    }
}

// ---------------------------------------------------------------------------
// Pass 1 (NEW): P = exp(xi @ xi^T) via MX-scaled fp8 MFMA (2x bf16 rate).
// xif holds e4m3(16*xi); both MFMA scales = 2^-4 undo the pre-scaling.
// 128x128 tile, 4 waves, each 64x64 = 2x2 of mfma_scale_f32_32x32x64_f8f6f4.
// LDS: rows of 64 B, 16-B chunks XOR-swizzled by (row>>1)&3 so both the
// global_load_lds staging (contiguous lane*16 dests, permuted global src)
// and the 32-B frag reads hit all 32 banks.
// ---------------------------------------------------------------------------
__global__ __launch_bounds__(256, 2)
void qk_fp8(const unsigned char* __restrict__ xif,  // [8192][1024] e4m3
            unsigned short* __restrict__ P,         // [8192][8192] bf16 bits
            float* __restrict__ lsum) {
  __shared__ __align__(16) unsigned char AsF[128 * 64];
  __shared__ __align__(16) unsigned char BsF[128 * 64];
  const int tid = threadIdx.x;
  const int lane = tid & 63;
  const int w = tid >> 6;
  const int i0 = blockIdx.y * 128;
  const int j0 = blockIdx.x * 128;

  f32x16 acc[2][2];
#pragma unroll
  for (int a = 0; a < 2; a++)
#pragma unroll
    for (int b = 0; b < 2; b++)
#pragma unroll
      for (int r = 0; r < 16; r++) acc[a][b][r] = 0.f;

  const int srow = lane >> 2;  // 0..15: row within 16-row staging group
  const int slot = lane & 3;   // 16-B chunk slot within the row
  const int kb = lane >> 5;    // frag k-block (0/1)
  const int l31 = lane & 31;

  for (int kk = 0; kk < DD; kk += 64) {
    __syncthreads();
#pragma unroll
    for (int t = 0; t < 2; t++) {
      const int r = w * 32 + t * 16 + srow;
      const int c = slot ^ ((r >> 1) & 3);  // logical chunk for this slot
      const unsigned char* ga = &xif[(size_t)(i0 + r) * DD + kk + c * 16];
      const unsigned char* gb = &xif[(size_t)(j0 + r) * DD + kk + c * 16];
      __builtin_amdgcn_global_load_lds((gptr_t)(const void*)ga,
                                       (lptr_t)(void*)&AsF[(w * 32 + t * 16) * 64],
                                       16, 0, 0);
      __builtin_amdgcn_global_load_lds((gptr_t)(const void*)gb,
                                       (lptr_t)(void*)&BsF[(w * 32 + t * 16) * 64],
                                       16, 0, 0);
    }
    __syncthreads();

    union frag_u { int4 q[2]; i8v v; };
    frag_u af[2], bf[2];
#pragma unroll
    for (int mi = 0; mi < 2; mi++) {
      const int ar = (w >> 1) * 64 + mi * 32 + l31;
      const int sw = (ar >> 1) & 3;
      af[mi].q[0] = *(const int4*)&AsF[ar * 64 + ((2 * kb + 0) ^ sw) * 16];
      af[mi].q[1] = *(const int4*)&AsF[ar * 64 + ((2 * kb + 1) ^ sw) * 16];
    }
#pragma unroll
    for (int nj = 0; nj < 2; nj++) {
      const int br = (w & 1) * 64 + nj * 32 + l31;
      const int sw = (br >> 1) & 3;
      bf[nj].q[0] = *(const int4*)&BsF[br * 64 + ((2 * kb + 0) ^ sw) * 16];
      bf[nj].q[1] = *(const int4*)&BsF[br * 64 + ((2 * kb + 1) ^ sw) * 16];
    }
#pragma unroll
    for (int mi = 0; mi < 2; mi++)
#pragma unroll
      for (int nj = 0; nj < 2; nj++)
        acc[mi][nj] = __builtin_amdgcn_mfma_scale_f32_32x32x64_f8f6f4(
            af[mi].v, bf[nj].v, acc[mi][nj], 0 /*cbsz: fp8*/, 0 /*blgp: fp8*/,
            0, SCALE_1_16, 0, SCALE_1_16);
  }

  // Epilogue: p = exp(s) -> P (bf16, 2-B coalesced stores); row sums of the
  // quantized values -> lsum atomics (matches pv's bf16 MFMA numerator).
  const int mbase = (w >> 1) * 64;
  const int nbase = (w & 1) * 64;
#pragma unroll
  for (int mi = 0; mi < 2; mi++) {
#pragma unroll
    for (int r = 0; r < 16; r++) {
      const int rl = mbase + mi * 32 + (r & 3) + 8 * (r >> 2) + 4 * (lane >> 5);
      float rs = 0.f;
#pragma unroll
      for (int nj = 0; nj < 2; nj++) {
        const float p = __expf(acc[mi][nj][r]);
        const unsigned short pb = f2bf(p);
        P[(size_t)(i0 + rl) * NQ + j0 + nbase + nj * 32 + l31] = pb;
        rs += bf2f(pb);
      }
#pragma unroll
      for (int m = 16; m >= 1; m >>= 1) rs += __shfl_xor(rs, m);
      if (l31 == 0) atomicAdd(&lsum[i0 + rl], rs);
    }
  }
}

// ---------------------------------------------------------------------------
// Pass 2: out = (P @ supT^T) / lsum[row], K = 8192 (bf16, unchanged).
// Grid: x = i-tile (64), y = n-tile (8) -> blocks sharing a P row-slab get
// the same bid%8 (XCD) for L2 reuse of P.
// ---------------------------------------------------------------------------
__global__ __launch_bounds__(256, 2)
void pv(const unsigned short* __restrict__ P,
        const unsigned short* __restrict__ supT,
        const float* __restrict__ lsum,
        float* __restrict__ out) {
  __shared__ __align__(16) unsigned short As[128 * 64];
  __shared__ __align__(16) unsigned short Bs[128 * 64];
  const int tid = threadIdx.x;
  const int i0 = blockIdx.x * 128;
  const int n0 = blockIdx.y * 128;

  f32x4 acc[4][4];
#pragma unroll
  for (int a = 0; a < 4; a++)
#pragma unroll
    for (int b = 0; b < 4; b++) acc[a][b] = (f32x4){0.f, 0.f, 0.f, 0.f};

  mfma_core<NQ, NQ, NQ>(P, supT, i0, n0, tid, As, Bs, acc);

  const int lane = tid & 63;
  const int w = tid >> 6;
  const int wr = (w >> 1) * 64, wc = (w & 1) * 64;
  const int l16 = lane & 15, lq = lane >> 4;
#pragma unroll
  for (int ti = 0; ti < 4; ti++) {
#pragma unroll
    for (int r = 0; r < 4; r++) {
      const int row = i0 + wr + 16 * ti + lq * 4 + r;
      const float linv = 1.f / lsum[row];
#pragma unroll
      for (int tj = 0; tj < 4; tj++) {
        const int col = n0 + wc + 16 * tj + l16;
        out[(size_t)row * DD + col] = acc[ti][tj][r] * linv;
      }
    }
  }
}

// ---------------------------------------------------------------------------
// Fallback fp32 path (round-1) — only if ws_size is too small.
// ---------------------------------------------------------------------------
#define BM 64
#define BN 64
#define BK 16

__global__ __launch_bounds__(256, 4)
void gemm64(const float* __restrict__ A, const float* __restrict__ B,
            float* __restrict__ C, int M, int N, int K) {
  __shared__ __align__(16) float As[BK][BM + 4];
  __shared__ __align__(16) float Bs[BK][BN + 4];
  const int tid = threadIdx.x;
  const int tx = tid & 15;
  const int ty = tid >> 4;
  const int row0 = blockIdx.y * BM;
  const int col0 = blockIdx.x * BN;
  float acc[4][4] = {};
  for (int k0 = 0; k0 < K; k0 += BK) {
    {
      const int r = tid >> 2;
      const int c4 = (tid & 3) * 4;
      const float4 v = *(const float4*)&A[(size_t)(row0 + r) * K + k0 + c4];
      As[c4 + 0][r] = v.x; As[c4 + 1][r] = v.y;
      As[c4 + 2][r] = v.z; As[c4 + 3][r] = v.w;
    }
    {
      const int r = tid >> 4;
      const int c4 = (tid & 15) * 4;
      *(float4*)&Bs[r][c4] = *(const float4*)&B[(size_t)(k0 + r) * N + col0 + c4];
    }
    __syncthreads();
#pragma unroll
    for (int k = 0; k < BK; k++) {
      const float4 a = *(const float4*)&As[k][4 * ty];
      const float4 b = *(const float4*)&Bs[k][4 * tx];
      const float av[4] = {a.x, a.y, a.z, a.w};
      const float bv[4] = {b.x, b.y, b.z, b.w};
#pragma unroll
      for (int i = 0; i < 4; i++)
#pragma unroll
        for (int j = 0; j < 4; j++)
          acc[i][j] += av[i] * bv[j];
    }
    __syncthreads();
  }
#pragma unroll
  for (int i = 0; i < 4; i++) {
    float4 o = {acc[i][0], acc[i][1], acc[i][2], acc[i][3]};
    *(float4*)&C[(size_t)(row0 + 4 * ty + i) * N + col0 + 4 * tx] = o;
  }
}

#define IT 32
#define JT 128
#define KC 32
#define CC 128
#define NCH (DD / CC)

__global__ __launch_bounds__(256, 1)
void fused_attn(const float* __restrict__ xi, const float* __restrict__ sup,
                float* __restrict__ out) {
  __shared__ __align__(16) float XiI[KC][IT + 4];
  __shared__ __align__(16) float XiJ[KC][JT + 4];
  __shared__ __align__(16) float Ps[JT][IT + 4];
  __shared__ __align__(16) float Vs[JT][CC + 4];
  __shared__ float lsum[IT];
  const int tid = threadIdx.x;
  const int i0 = blockIdx.x * IT;
  const int ry = tid >> 5;
  const int cx = tid & 31;
  if (tid < IT) lsum[tid] = 0.f;
  float oacc[NCH][4][4];
#pragma unroll
  for (int ch = 0; ch < NCH; ch++)
#pragma unroll
    for (int i = 0; i < 4; i++)
#pragma unroll
      for (int j = 0; j < 4; j++) oacc[ch][i][j] = 0.f;
  for (int j0 = 0; j0 < NQ; j0 += JT) {
    float sacc[4][4] = {};
    for (int kc = 0; kc < DD; kc += KC) {
      __syncthreads();
      {
        const int r = tid >> 3;
        const int k4 = (tid & 7) * 4;
        const float4 v = *(const float4*)&xi[(size_t)(i0 + r) * DD + kc + k4];
        XiI[k4 + 0][r] = v.x; XiI[k4 + 1][r] = v.y;
        XiI[k4 + 2][r] = v.z; XiI[k4 + 3][r] = v.w;
      }
#pragma unroll
      for (int i = 0; i < 4; i++) {
        const int idx = tid + i * 256;
        const int r = idx >> 3;
        const int k4 = (idx & 7) * 4;
        const float4 v = *(const float4*)&xi[(size_t)(j0 + r) * DD + kc + k4];
        XiJ[k4 + 0][r] = v.x; XiJ[k4 + 1][r] = v.y;
        XiJ[k4 + 2][r] = v.z; XiJ[k4 + 3][r] = v.w;
      }
      __syncthreads();
#pragma unroll
      for (int k = 0; k < KC; k++) {
        const float4 a = *(const float4*)&XiI[k][4 * ry];
        const float4 b = *(const float4*)&XiJ[k][4 * cx];
        const float av[4] = {a.x, a.y, a.z, a.w};
        const float bv[4] = {b.x, b.y, b.z, b.w};
#pragma unroll
        for (int i = 0; i < 4; i++)
#pragma unroll
          for (int j = 0; j < 4; j++)
            sacc[i][j] += av[i] * bv[j];
      }
    }
    __syncthreads();
    float rsv[4] = {0.f, 0.f, 0.f, 0.f};
#pragma unroll
    for (int i = 0; i < 4; i++)
#pragma unroll
      for (int j = 0; j < 4; j++) {
        const float p = __expf(sacc[i][j]);
        Ps[4 * cx + j][4 * ry + i] = p;
        rsv[i] += p;
      }
#pragma unroll
    for (int m = 16; m >= 1; m >>= 1)
#pragma unroll
      for (int i = 0; i < 4; i++) rsv[i] += __shfl_xor(rsv[i], m);
    if (cx == 0) {
#pragma unroll
      for (int i = 0; i < 4; i++) lsum[4 * ry + i] += rsv[i];
    }
    for (int ch = 0; ch < NCH; ch++) {
      __syncthreads();
#pragma unroll
      for (int i = 0; i < 16; i++) {
        const int idx = tid + i * 256;
        const int r = idx >> 5;
        const int c4 = (idx & 31) * 4;
        *(float4*)&Vs[r][c4] =
            *(const float4*)&sup[(size_t)(j0 + r) * DD + ch * CC + c4];
      }
      __syncthreads();
#pragma unroll 4
      for (int jp = 0; jp < JT; jp++) {
        const float4 p = *(const float4*)&Ps[jp][4 * ry];
        const float4 v = *(const float4*)&Vs[jp][4 * cx];
        const float pvv[4] = {p.x, p.y, p.z, p.w};
        const float vv[4] = {v.x, v.y, v.z, v.w};
#pragma unroll
        for (int i = 0; i < 4; i++)
#pragma unroll
          for (int j = 0; j < 4; j++)
            oacc[ch][i][j] += pvv[i] * vv[j];
      }
    }
  }
  __syncthreads();
  float linv[4];
#pragma unroll
  for (int i = 0; i < 4; i++) linv[i] = 1.f / lsum[4 * ry + i];
#pragma unroll
  for (int ch = 0; ch < NCH; ch++)
#pragma unroll
    for (int i = 0; i < 4; i++) {
      float4 o = {oacc[ch][i][0] * linv[i], oacc[ch][i][1] * linv[i],
                  oacc[ch][i][2] * linv[i], oacc[ch][i][3] * linv[i]};
      *(float4*)&out[(size_t)(i0 + 4 * ry + i) * DD + ch * CC + 4 * cx] = o;
    }
}

// ---------------------------------------------------------------------------
// Launch. ws layout (MFMA path, NEED = 152 MB + 32 KB):
//   P    : [0, 128MB)    bf16 [8192][8192]
//   xif  : [128,136MB)   e4m3 [8192][1024] (= fp8(16*xi))
//   supT : [136,152MB)   bf16 [1024][8192]
//   lsum : [152MB,+32KB) fp32 [8192]
//   transients (consumed before P is written, alias the P region):
//     xb [0,16MB) bf16 [8192][1024];  tiT [16,18MB);  wT [18,20MB)
// NOTE: reference uses transferi for BOTH projections; transferj unused.
// ---------------------------------------------------------------------------
extern "C" void kernel_launch(void* const* d_in, const int* in_sizes, int n_in,
                              void* d_out, int out_size, void* d_ws, size_t ws_size,
                              hipStream_t stream) {
  const float* x  = (const float*)d_in[0];
  const float* wt = (const float*)d_in[1];
  const float* ti = (const float*)d_in[2];
  float* out = (float*)d_out;

  char* ws = (char*)d_ws;
  const size_t MB = 1024 * 1024;
  const size_t NEED = 152 * MB + NQ * sizeof(float);

  if (ws_size >= NEED) {
    unsigned short* P    = (unsigned short*)ws;
    unsigned char*  xif  = (unsigned char*)(ws + 128 * MB);
    unsigned short* supT = (unsigned short*)(ws + 136 * MB);
    float* lsum          = (float*)(ws + 152 * MB);
    unsigned short* xb   = (unsigned short*)ws;             // transient in P
    unsigned short* tiT  = (unsigned short*)(ws + 16 * MB); // transient in P
    unsigned short* wT   = (unsigned short*)(ws + 18 * MB); // transient in P

    const int n4 = NQ * DD / 4;
    f32_to_bf16<<<(n4 + 255) / 256, 256, 0, stream>>>(x, xb, n4);
    transpose_cvt<<<dim3(32, 32), 256, 0, stream>>>(ti, tiT, DD, DD);
    transpose_cvt<<<dim3(32, 32), 256, 0, stream>>>(wt, wT, DD, DD);

    // xif[m][n] = e4m3(16 * sum_k xb[m][k]*ti[k][n])
    proj_gemm<DD, true><<<dim3(DD / 128, NQ / 128), 256, 0, stream>>>(xb, tiT, xif);
    // supT[n][m] = bf16(sum_k W[k][n]*x[m][k])
    proj_gemm<NQ, false><<<dim3(NQ / 128, DD / 128), 256, 0, stream>>>(wT, xb, supT);

    hipMemsetAsync(lsum, 0, NQ * sizeof(float), stream);
    qk_fp8<<<dim3(NQ / 128, NQ / 128), 256, 0, stream>>>(xif, P, lsum);
    pv<<<dim3(NQ / 128, DD / 128), 256, 0, stream>>>(P, supT, lsum, out);
  } else {
    float* xi32  = (float*)ws;
    float* sup32 = (float*)(ws + 32 * MB);
    dim3 ggrid(DD / BN, NQ / BM);
    gemm64<<<ggrid, 256, 0, stream>>>(x, ti, xi32, NQ, DD, DD);
    gemm64<<<ggrid, 256, 0, stream>>>(x, wt, sup32, NQ, DD, DD);
    fused_attn<<<NQ / IT, 256, 0, stream>>>(xi32, sup32, out);
  }
}

// Round 5
// 747.822 us; speedup vs baseline: 1.0072x; 1.0072x over previous
//
#include <hip/hip_runtime.h>
#include <hip/hip_bf16.h>
#include <cstddef>

// Problem constants (match reference).
#define NQ 8192
#define DD 1024

typedef __attribute__((ext_vector_type(8))) short s8v;     // 8 bf16 (4 VGPR)
typedef __attribute__((ext_vector_type(8))) int i8v;       // 32 fp8 bytes (8 VGPR)
typedef __attribute__((ext_vector_type(4))) float f32x4;   // 16x16 C/D frag
typedef __attribute__((ext_vector_type(16))) float f32x16; // 32x32 C/D frag

typedef const __attribute__((address_space(1))) unsigned int* gptr_t;
typedef __attribute__((address_space(3))) unsigned int* lptr_t;

#define SCALE_1_16 0x7B7B7B7Bu  // E8M0 123 = 2^-4 in every byte

__device__ inline unsigned short f2bf(float f) {
  union { float f; unsigned u; } v; v.f = f;
  unsigned r = (v.u + 0x7FFFu + ((v.u >> 16) & 1u)) >> 16;  // RNE
  return (unsigned short)r;
}
__device__ inline float bf2f(unsigned short u) {
  union { unsigned u; float f; } v; v.u = ((unsigned)u) << 16;
  return v.f;
}

// f32 -> OCP e4m3 bits, RNE, clamp to +-448.
__device__ inline unsigned char f2e4m3(float x) {
  union { float f; unsigned u; } v; v.f = x;
  const unsigned s = (v.u >> 31) << 7;
  unsigned au = v.u & 0x7FFFFFFFu;
  if (au > 0x43E00000u) au = 0x43E00000u;  // clamp |x| to 448.0
  if (au >= 0x3C800000u) {                 // |x| >= 2^-6: e4m3 normal
    const unsigned rounded = au + 0x7FFFFu + ((au >> 20) & 1u);  // RNE @ 3 mant
    const unsigned e8 = ((rounded >> 23) & 0xFF) - 120u;         // -127+7
    const unsigned m8 = (rounded >> 20) & 7u;
    return (unsigned char)(s | (e8 << 3) | m8);
  } else {                                 // subnormal
    union { unsigned u; float f; } a; a.u = au;
    const unsigned q = (unsigned)rintf(a.f * 512.0f);  // 0..8
    return (unsigned char)(s | q);
  }
}

// Register-only combine of two 16-B LDS loads into one fp8 MFMA operand.
// (NO union type-pun: unions block SROA -> scratch spill -> R4's 1.3 GB of
// spurious HBM traffic. Element inserts stay in VGPRs.)
__device__ inline i8v make_i8v(int4 a, int4 b) {
  i8v v;
  v[0] = a.x; v[1] = a.y; v[2] = a.z; v[3] = a.w;
  v[4] = b.x; v[5] = b.y; v[6] = b.z; v[7] = b.w;
  return v;
}

// ---------------------------------------------------------------------------
// m97-style bf16 MFMA main loop: C(128x128) += A(128xK) @ B(128xK)^T.
// BK=64, global_load_lds dwordx4 staging, 4 waves, each 64x64 via 4x4 of
// 16x16x32 bf16 MFMA. Used by proj_gemm and pv.
// ---------------------------------------------------------------------------
template <int KDIM, int ASTR, int BSTR>
__device__ inline void mfma_core(const unsigned short* __restrict__ A,
                                 const unsigned short* __restrict__ B,
                                 int i0, int j0, int tid,
                                 unsigned short* AsU, unsigned short* BsU,
                                 f32x4 (&acc)[4][4]) {
  const int lane = tid & 63;
  const int w = tid >> 6;
  const int wr = (w >> 1) * 64;
  const int wc = (w & 1) * 64;
  const int l16 = lane & 15;
  const int lq = lane >> 4;
  const int srow = lane >> 3;
  const int scol = (lane & 7) * 8;

  for (int kk = 0; kk < KDIM; kk += 64) {
    __syncthreads();
#pragma unroll
    for (int t = 0; t < 4; t++) {
      const int r0 = w * 32 + t * 8;
      const unsigned short* g = &A[(size_t)(i0 + r0 + srow) * ASTR + kk + scol];
      __builtin_amdgcn_global_load_lds((gptr_t)(const void*)g,
                                       (lptr_t)(void*)&AsU[r0 * 64], 16, 0, 0);
    }
#pragma unroll
    for (int t = 0; t < 4; t++) {
      const int r0 = w * 32 + t * 8;
      const unsigned short* g = &B[(size_t)(j0 + r0 + srow) * BSTR + kk + scol];
      __builtin_amdgcn_global_load_lds((gptr_t)(const void*)g,
                                       (lptr_t)(void*)&BsU[r0 * 64], 16, 0, 0);
    }
    __syncthreads();

    s8v af[4][2], bf[4][2];
#pragma unroll
    for (int t = 0; t < 4; t++)
#pragma unroll
      for (int s = 0; s < 2; s++) {
        af[t][s] = *(const s8v*)&AsU[(wr + 16 * t + l16) * 64 + s * 32 + lq * 8];
        bf[t][s] = *(const s8v*)&BsU[(wc + 16 * t + l16) * 64 + s * 32 + lq * 8];
      }
#pragma unroll
    for (int s = 0; s < 2; s++)
#pragma unroll
      for (int a = 0; a < 4; a++)
#pragma unroll
        for (int b = 0; b < 4; b++)
          acc[a][b] = __builtin_amdgcn_mfma_f32_16x16x32_bf16(
              af[a][s], bf[b][s], acc[a][b], 0, 0, 0);
  }
}

// ---------------------------------------------------------------------------
// fp32 -> bf16 elementwise.
// ---------------------------------------------------------------------------
__global__ void f32_to_bf16(const float* __restrict__ in,
                            unsigned short* __restrict__ out, int n4) {
  int i = (blockIdx.x * blockDim.x + threadIdx.x);
  if (i < n4) {
    const float4 v = *(const float4*)&in[i * 4];
    ushort4 o;
    o.x = f2bf(v.x); o.y = f2bf(v.y); o.z = f2bf(v.z); o.w = f2bf(v.w);
    *(ushort4*)&out[i * 4] = o;
  }
}

// ---------------------------------------------------------------------------
// fp32 [R][C] -> bf16 [C][R] transpose+convert (32x32 LDS tiles).
// ---------------------------------------------------------------------------
__global__ void transpose_cvt(const float* __restrict__ in,
                              unsigned short* __restrict__ out, int R, int C) {
  __shared__ float t[32][33];
  const int bx = blockIdx.x;
  const int by = blockIdx.y;
  const int x = threadIdx.x & 31;
  const int y = threadIdx.x >> 5;
#pragma unroll
  for (int i = 0; i < 32; i += 8)
    t[y + i][x] = in[(size_t)(by * 32 + y + i) * C + bx * 32 + x];
  __syncthreads();
#pragma unroll
  for (int i = 0; i < 32; i += 8)
    out[(size_t)(bx * 32 + y + i) * R + by * 32 + x] = f2bf(t[x][y + i]);
}

// ---------------------------------------------------------------------------
// Projection GEMM: C[m][n] = sum_k A[m][k] * BT[n][k], bf16 in, K=1024.
// FP8OUT=true writes e4m3(16*value) for the MX qk pass.
// ---------------------------------------------------------------------------
template <int NST, bool FP8OUT>
__global__ __launch_bounds__(256, 2)
void proj_gemm(const unsigned short* __restrict__ A,
               const unsigned short* __restrict__ BT,
               void* __restrict__ Cout) {
  __shared__ __align__(16) unsigned short As[128 * 64];
  __shared__ __align__(16) unsigned short Bs[128 * 64];
  const int tid = threadIdx.x;
  const int m0 = blockIdx.y * 128;
  const int n0 = blockIdx.x * 128;

  f32x4 acc[4][4];
#pragma unroll
  for (int a = 0; a < 4; a++)
#pragma unroll
    for (int b = 0; b < 4; b++) acc[a][b] = (f32x4){0.f, 0.f, 0.f, 0.f};

  mfma_core<DD, DD, DD>(A, BT, m0, n0, tid, As, Bs, acc);

  const int lane = tid & 63;
  const int w = tid >> 6;
  const int wr = (w >> 1) * 64, wc = (w & 1) * 64;
  const int l16 = lane & 15, lq = lane >> 4;
#pragma unroll
  for (int ti = 0; ti < 4; ti++)
#pragma unroll
    for (int r = 0; r < 4; r++) {
      const int row = m0 + wr + 16 * ti + lq * 4 + r;
#pragma unroll
      for (int tj = 0; tj < 4; tj++) {
        const int col = n0 + wc + 16 * tj + l16;
        if (FP8OUT) {
          ((unsigned char*)Cout)[(size_t)row * NST + col] =
              f2e4m3(acc[ti][tj][r] * 16.f);
        } else {
          ((unsigned short*)Cout)[(size_t)row * NST + col] = f2bf(acc[ti][tj][r]);
        }
      }
    }
}

// ---------------------------------------------------------------------------
// Pass 1: P = exp(xi @ xi^T) via MX-scaled fp8 MFMA (2x bf16 rate).
// xif holds e4m3(16*xi); both MFMA scales = 2^-4 undo the pre-scaling.
// 128x128 tile, 4 waves, each 64x64 = 2x2 of mfma_scale_f32_32x32x64_f8f6f4.
// LDS: 64-B rows, 16-B chunks XOR-swizzled by (row>>1)&3.
// ---------------------------------------------------------------------------
__global__ __launch_bounds__(256, 2)
void qk_fp8(const unsigned char* __restrict__ xif,  // [8192][1024] e4m3
            unsigned short* __restrict__ P,         // [8192][8192] bf16 bits
            float* __restrict__ lsum) {
  __shared__ __align__(16) unsigned char AsF[128 * 64];
  __shared__ __align__(16) unsigned char BsF[128 * 64];
  const int tid = threadIdx.x;
  const int lane = tid & 63;
  const int w = tid >> 6;
  const int i0 = blockIdx.y * 128;
  const int j0 = blockIdx.x * 128;

  f32x16 acc[2][2];
#pragma unroll
  for (int a = 0; a < 2; a++)
#pragma unroll
    for (int b = 0; b < 2; b++)
#pragma unroll
      for (int r = 0; r < 16; r++) acc[a][b][r] = 0.f;

  const int srow = lane >> 2;  // 0..15: row within 16-row staging group
  const int slot = lane & 3;   // 16-B chunk slot within the row
  const int kb = lane >> 5;    // frag k-block (0/1)
  const int l31 = lane & 31;

  for (int kk = 0; kk < DD; kk += 64) {
    __syncthreads();
#pragma unroll
    for (int t = 0; t < 2; t++) {
      const int r = w * 32 + t * 16 + srow;
      const int c = slot ^ ((r >> 1) & 3);  // logical chunk for this slot
      const unsigned char* ga = &xif[(size_t)(i0 + r) * DD + kk + c * 16];
      const unsigned char* gb = &xif[(size_t)(j0 + r) * DD + kk + c * 16];
      __builtin_amdgcn_global_load_lds((gptr_t)(const void*)ga,
                                       (lptr_t)(void*)&AsF[(w * 32 + t * 16) * 64],
                                       16, 0, 0);
      __builtin_amdgcn_global_load_lds((gptr_t)(const void*)gb,
                                       (lptr_t)(void*)&BsF[(w * 32 + t * 16) * 64],
                                       16, 0, 0);
    }
    __syncthreads();

    i8v af[2], bf[2];
#pragma unroll
    for (int mi = 0; mi < 2; mi++) {
      const int ar = (w >> 1) * 64 + mi * 32 + l31;
      const int sw = (ar >> 1) & 3;
      const int4 q0 = *(const int4*)&AsF[ar * 64 + ((2 * kb + 0) ^ sw) * 16];
      const int4 q1 = *(const int4*)&AsF[ar * 64 + ((2 * kb + 1) ^ sw) * 16];
      af[mi] = make_i8v(q0, q1);
    }
#pragma unroll
    for (int nj = 0; nj < 2; nj++) {
      const int br = (w & 1) * 64 + nj * 32 + l31;
      const int sw = (br >> 1) & 3;
      const int4 q0 = *(const int4*)&BsF[br * 64 + ((2 * kb + 0) ^ sw) * 16];
      const int4 q1 = *(const int4*)&BsF[br * 64 + ((2 * kb + 1) ^ sw) * 16];
      bf[nj] = make_i8v(q0, q1);
    }
#pragma unroll
    for (int mi = 0; mi < 2; mi++)
#pragma unroll
      for (int nj = 0; nj < 2; nj++)
        acc[mi][nj] = __builtin_amdgcn_mfma_scale_f32_32x32x64_f8f6f4(
            af[mi], bf[nj], acc[mi][nj], 0 /*cbsz: fp8*/, 0 /*blgp: fp8*/,
            0, SCALE_1_16, 0, SCALE_1_16);
  }

  // Epilogue: p = exp(s) -> P (bf16); row sums of quantized values -> lsum.
  const int mbase = (w >> 1) * 64;
  const int nbase = (w & 1) * 64;
#pragma unroll
  for (int mi = 0; mi < 2; mi++) {
#pragma unroll
    for (int r = 0; r < 16; r++) {
      const int rl = mbase + mi * 32 + (r & 3) + 8 * (r >> 2) + 4 * (lane >> 5);
      float rs = 0.f;
#pragma unroll
      for (int nj = 0; nj < 2; nj++) {
        const float p = __expf(acc[mi][nj][r]);
        const unsigned short pb = f2bf(p);
        P[(size_t)(i0 + rl) * NQ + j0 + nbase + nj * 32 + l31] = pb;
        rs += bf2f(pb);
      }
#pragma unroll
      for (int m = 16; m >= 1; m >>= 1) rs += __shfl_xor(rs, m);
      if (l31 == 0) atomicAdd(&lsum[i0 + rl], rs);
    }
  }
}

// ---------------------------------------------------------------------------
// Pass 2: out = (P @ supT^T) / lsum[row], K = 8192 (bf16).
// Grid: x = i-tile (64), y = n-tile (8) -> blocks sharing a P row-slab get
// the same bid%8 (XCD) for L2 reuse of P.
// ---------------------------------------------------------------------------
__global__ __launch_bounds__(256, 2)
void pv(const unsigned short* __restrict__ P,
        const unsigned short* __restrict__ supT,
        const float* __restrict__ lsum,
        float* __restrict__ out) {
  __shared__ __align__(16) unsigned short As[128 * 64];
  __shared__ __align__(16) unsigned short Bs[128 * 64];
  const int tid = threadIdx.x;
  const int i0 = blockIdx.x * 128;
  const int n0 = blockIdx.y * 128;

  f32x4 acc[4][4];
#pragma unroll
  for (int a = 0; a < 4; a++)
#pragma unroll
    for (int b = 0; b < 4; b++) acc[a][b] = (f32x4){0.f, 0.f, 0.f, 0.f};

  mfma_core<NQ, NQ, NQ>(P, supT, i0, n0, tid, As, Bs, acc);

  const int lane = tid & 63;
  const int w = tid >> 6;
  const int wr = (w >> 1) * 64, wc = (w & 1) * 64;
  const int l16 = lane & 15, lq = lane >> 4;
#pragma unroll
  for (int ti = 0; ti < 4; ti++) {
#pragma unroll
    for (int r = 0; r < 4; r++) {
      const int row = i0 + wr + 16 * ti + lq * 4 + r;
      const float linv = 1.f / lsum[row];
#pragma unroll
      for (int tj = 0; tj < 4; tj++) {
        const int col = n0 + wc + 16 * tj + l16;
        out[(size_t)row * DD + col] = acc[ti][tj][r] * linv;
      }
    }
  }
}

// ---------------------------------------------------------------------------
// Fallback fp32 path (round-1) — only if ws_size is too small.
// ---------------------------------------------------------------------------
#define BM 64
#define BN 64
#define BK 16

__global__ __launch_bounds__(256, 4)
void gemm64(const float* __restrict__ A, const float* __restrict__ B,
            float* __restrict__ C, int M, int N, int K) {
  __shared__ __align__(16) float As[BK][BM + 4];
  __shared__ __align__(16) float Bs[BK][BN + 4];
  const int tid = threadIdx.x;
  const int tx = tid & 15;
  const int ty = tid >> 4;
  const int row0 = blockIdx.y * BM;
  const int col0 = blockIdx.x * BN;
  float acc[4][4] = {};
  for (int k0 = 0; k0 < K; k0 += BK) {
    {
      const int r = tid >> 2;
      const int c4 = (tid & 3) * 4;
      const float4 v = *(const float4*)&A[(size_t)(row0 + r) * K + k0 + c4];
      As[c4 + 0][r] = v.x; As[c4 + 1][r] = v.y;
      As[c4 + 2][r] = v.z; As[c4 + 3][r] = v.w;
    }
    {
      const int r = tid >> 4;
      const int c4 = (tid & 15) * 4;
      *(float4*)&Bs[r][c4] = *(const float4*)&B[(size_t)(k0 + r) * N + col0 + c4];
    }
    __syncthreads();
#pragma unroll
    for (int k = 0; k < BK; k++) {
      const float4 a = *(const float4*)&As[k][4 * ty];
      const float4 b = *(const float4*)&Bs[k][4 * tx];
      const float av[4] = {a.x, a.y, a.z, a.w};
      const float bv[4] = {b.x, b.y, b.z, b.w};
#pragma unroll
      for (int i = 0; i < 4; i++)
#pragma unroll
        for (int j = 0; j < 4; j++)
          acc[i][j] += av[i] * bv[j];
    }
    __syncthreads();
  }
#pragma unroll
  for (int i = 0; i < 4; i++) {
    float4 o = {acc[i][0], acc[i][1], acc[i][2], acc[i][3]};
    *(float4*)&C[(size_t)(row0 + 4 * ty + i) * N + col0 + 4 * tx] = o;
  }
}

#define IT 32
#define JT 128
#define KC 32
#define CC 128
#define NCH (DD / CC)

__global__ __launch_bounds__(256, 1)
void fused_attn(const float* __restrict__ xi, const float* __restrict__ sup,
                float* __restrict__ out) {
  __shared__ __align__(16) float XiI[KC][IT + 4];
  __shared__ __align__(16) float XiJ[KC][JT + 4];
  __shared__ __align__(16) float Ps[JT][IT + 4];
  __shared__ __align__(16) float Vs[JT][CC + 4];
  __shared__ float lsum[IT];
  const int tid = threadIdx.x;
  const int i0 = blockIdx.x * IT;
  const int ry = tid >> 5;
  const int cx = tid & 31;
  if (tid < IT) lsum[tid] = 0.f;
  float oacc[NCH][4][4];
#pragma unroll
  for (int ch = 0; ch < NCH; ch++)
#pragma unroll
    for (int i = 0; i < 4; i++)
#pragma unroll
      for (int j = 0; j < 4; j++) oacc[ch][i][j] = 0.f;
  for (int j0 = 0; j0 < NQ; j0 += JT) {
    float sacc[4][4] = {};
    for (int kc = 0; kc < DD; kc += KC) {
      __syncthreads();
      {
        const int r = tid >> 3;
        const int k4 = (tid & 7) * 4;
        const float4 v = *(const float4*)&xi[(size_t)(i0 + r) * DD + kc + k4];
        XiI[k4 + 0][r] = v.x; XiI[k4 + 1][r] = v.y;
        XiI[k4 + 2][r] = v.z; XiI[k4 + 3][r] = v.w;
      }
#pragma unroll
      for (int i = 0; i < 4; i++) {
        const int idx = tid + i * 256;
        const int r = idx >> 3;
        const int k4 = (idx & 7) * 4;
        const float4 v = *(const float4*)&xi[(size_t)(j0 + r) * DD + kc + k4];
        XiJ[k4 + 0][r] = v.x; XiJ[k4 + 1][r] = v.y;
        XiJ[k4 + 2][r] = v.z; XiJ[k4 + 3][r] = v.w;
      }
      __syncthreads();
#pragma unroll
      for (int k = 0; k < KC; k++) {
        const float4 a = *(const float4*)&XiI[k][4 * ry];
        const float4 b = *(const float4*)&XiJ[k][4 * cx];
        const float av[4] = {a.x, a.y, a.z, a.w};
        const float bv[4] = {b.x, b.y, b.z, b.w};
#pragma unroll
        for (int i = 0; i < 4; i++)
#pragma unroll
          for (int j = 0; j < 4; j++)
            sacc[i][j] += av[i] * bv[j];
      }
    }
    __syncthreads();
    float rsv[4] = {0.f, 0.f, 0.f, 0.f};
#pragma unroll
    for (int i = 0; i < 4; i++)
#pragma unroll
      for (int j = 0; j < 4; j++) {
        const float p = __expf(sacc[i][j]);
        Ps[4 * cx + j][4 * ry + i] = p;
        rsv[i] += p;
      }
#pragma unroll
    for (int m = 16; m >= 1; m >>= 1)
#pragma unroll
      for (int i = 0; i < 4; i++) rsv[i] += __shfl_xor(rsv[i], m);
    if (cx == 0) {
#pragma unroll
      for (int i = 0; i < 4; i++) lsum[4 * ry + i] += rsv[i];
    }
    for (int ch = 0; ch < NCH; ch++) {
      __syncthreads();
#pragma unroll
      for (int i = 0; i < 16; i++) {
        const int idx = tid + i * 256;
        const int r = idx >> 5;
        const int c4 = (idx & 31) * 4;
        *(float4*)&Vs[r][c4] =
            *(const float4*)&sup[(size_t)(j0 + r) * DD + ch * CC + c4];
      }
      __syncthreads();
#pragma unroll 4
      for (int jp = 0; jp < JT; jp++) {
        const float4 p = *(const float4*)&Ps[jp][4 * ry];
        const float4 v = *(const float4*)&Vs[jp][4 * cx];
        const float pvv[4] = {p.x, p.y, p.z, p.w};
        const float vv[4] = {v.x, v.y, v.z, v.w};
#pragma unroll
        for (int i = 0; i < 4; i++)
#pragma unroll
          for (int j = 0; j < 4; j++)
            oacc[ch][i][j] += pvv[i] * vv[j];
      }
    }
  }
  __syncthreads();
  float linv[4];
#pragma unroll
  for (int i = 0; i < 4; i++) linv[i] = 1.f / lsum[4 * ry + i];
#pragma unroll
  for (int ch = 0; ch < NCH; ch++)
#pragma unroll
    for (int i = 0; i < 4; i++) {
      float4 o = {oacc[ch][i][0] * linv[i], oacc[ch][i][1] * linv[i],
                  oacc[ch][i][2] * linv[i], oacc[ch][i][3] * linv[i]};
      *(float4*)&out[(size_t)(i0 + 4 * ry + i) * DD + ch * CC + 4 * cx] = o;
    }
}

// ---------------------------------------------------------------------------
// Launch. ws layout (MFMA path, NEED = 152 MB + 32 KB):
//   P    : [0, 128MB)    bf16 [8192][8192]
//   xif  : [128,136MB)   e4m3 [8192][1024] (= fp8(16*xi))
//   supT : [136,152MB)   bf16 [1024][8192]
//   lsum : [152MB,+32KB) fp32 [8192]
//   transients (consumed before P is written, alias the P region):
//     xb [0,16MB) bf16 [8192][1024];  tiT [16,18MB);  wT [18,20MB)
// NOTE: reference uses transferi for BOTH projections; transferj unused.
// ---------------------------------------------------------------------------
extern "C" void kernel_launch(void* const* d_in, const int* in_sizes, int n_in,
                              void* d_out, int out_size, void* d_ws, size_t ws_size,
                              hipStream_t stream) {
  const float* x  = (const float*)d_in[0];
  const float* wt = (const float*)d_in[1];
  const float* ti = (const float*)d_in[2];
  float* out = (float*)d_out;

  char* ws = (char*)d_ws;
  const size_t MB = 1024 * 1024;
  const size_t NEED = 152 * MB + NQ * sizeof(float);

  if (ws_size >= NEED) {
    unsigned short* P    = (unsigned short*)ws;
    unsigned char*  xif  = (unsigned char*)(ws + 128 * MB);
    unsigned short* supT = (unsigned short*)(ws + 136 * MB);
    float* lsum          = (float*)(ws + 152 * MB);
    unsigned short* xb   = (unsigned short*)ws;             // transient in P
    unsigned short* tiT  = (unsigned short*)(ws + 16 * MB); // transient in P
    unsigned short* wT   = (unsigned short*)(ws + 18 * MB); // transient in P

    const int n4 = NQ * DD / 4;
    f32_to_bf16<<<(n4 + 255) / 256, 256, 0, stream>>>(x, xb, n4);
    transpose_cvt<<<dim3(32, 32), 256, 0, stream>>>(ti, tiT, DD, DD);
    transpose_cvt<<<dim3(32, 32), 256, 0, stream>>>(wt, wT, DD, DD);

    // xif[m][n] = e4m3(16 * sum_k xb[m][k]*ti[k][n])
    proj_gemm<DD, true><<<dim3(DD / 128, NQ / 128), 256, 0, stream>>>(xb, tiT, xif);
    // supT[n][m] = bf16(sum_k W[k][n]*x[m][k])
    proj_gemm<NQ, false><<<dim3(NQ / 128, DD / 128), 256, 0, stream>>>(wT, xb, supT);

    hipMemsetAsync(lsum, 0, NQ * sizeof(float), stream);
    qk_fp8<<<dim3(NQ / 128, NQ / 128), 256, 0, stream>>>(xif, P, lsum);
    pv<<<dim3(NQ / 128, DD / 128), 256, 0, stream>>>(P, supT, lsum, out);
  } else {
    float* xi32  = (float*)ws;
    float* sup32 = (float*)(ws + 32 * MB);
    dim3 ggrid(DD / BN, NQ / BM);
    gemm64<<<ggrid, 256, 0, stream>>>(x, ti, xi32, NQ, DD, DD);
    gemm64<<<ggrid, 256, 0, stream>>>(x, wt, sup32, NQ, DD, DD);
    fused_attn<<<NQ / IT, 256, 0, stream>>>(xi32, sup32, out);
  }
}

// Round 6
// 434.810 us; speedup vs baseline: 1.7323x; 1.7199x over previous
//
#include <hip/hip_runtime.h>
#include <hip/hip_bf16.h>
#include <cstddef>

// Problem constants (match reference).
#define NQ 8192
#define DD 1024

typedef __attribute__((ext_vector_type(8))) short s8v;     // 8 bf16 (4 VGPR)
typedef __attribute__((ext_vector_type(8))) int i8v;       // 32 fp8 bytes (8 VGPR)
typedef __attribute__((ext_vector_type(4))) float f32x4;   // 16x16 C/D frag
typedef __attribute__((ext_vector_type(16))) float f32x16; // 32x32 C/D frag

typedef const __attribute__((address_space(1))) unsigned int* gptr_t;
typedef __attribute__((address_space(3))) unsigned int* lptr_t;

#define SCALE_1_16 0x7B7B7B7Bu  // E8M0 123 = 2^-4 in every byte

__device__ inline unsigned short f2bf(float f) {
  union { float f; unsigned u; } v; v.f = f;
  unsigned r = (v.u + 0x7FFFu + ((v.u >> 16) & 1u)) >> 16;  // RNE
  return (unsigned short)r;
}
__device__ inline float bf2f(unsigned short u) {
  union { unsigned u; float f; } v; v.u = ((unsigned)u) << 16;
  return v.f;
}
__device__ inline float bits2f(unsigned u) {
  union { unsigned u; float f; } v; v.u = u;
  return v.f;
}

// f32 -> OCP e4m3 bits, RNE, clamp to +-448.
__device__ inline unsigned char f2e4m3(float x) {
  union { float f; unsigned u; } v; v.f = x;
  const unsigned s = (v.u >> 31) << 7;
  unsigned au = v.u & 0x7FFFFFFFu;
  if (au > 0x43E00000u) au = 0x43E00000u;  // clamp |x| to 448.0
  if (au >= 0x3C800000u) {                 // |x| >= 2^-6: e4m3 normal
    const unsigned rounded = au + 0x7FFFFu + ((au >> 20) & 1u);  // RNE @ 3 mant
    const unsigned e8 = ((rounded >> 23) & 0xFF) - 120u;         // -127+7
    const unsigned m8 = (rounded >> 20) & 7u;
    return (unsigned char)(s | (e8 << 3) | m8);
  } else {                                 // subnormal
    union { unsigned u; float f; } a; a.u = au;
    const unsigned q = (unsigned)rintf(a.f * 512.0f);  // 0..8
    return (unsigned char)(s | q);
  }
}

// Register-only combine of two 16-B LDS loads into one fp8 MFMA operand.
__device__ inline i8v make_i8v(int4 a, int4 b) {
  i8v v;
  v[0] = a.x; v[1] = a.y; v[2] = a.z; v[3] = a.w;
  v[4] = b.x; v[5] = b.y; v[6] = b.z; v[7] = b.w;
  return v;
}

// ---------------------------------------------------------------------------
// m97-style bf16 MFMA main loop: C(128x128) += A(128xK) @ B(128xK)^T.
// BK=64, global_load_lds dwordx4 staging, 4 waves, each 64x64 via 4x4 of
// 16x16x32 bf16 MFMA. Used by proj_gemm and pv.
// ---------------------------------------------------------------------------
template <int KDIM, int ASTR, int BSTR>
__device__ inline void mfma_core(const unsigned short* __restrict__ A,
                                 const unsigned short* __restrict__ B,
                                 int i0, int j0, int tid,
                                 unsigned short* AsU, unsigned short* BsU,
                                 f32x4 (&acc)[4][4]) {
  const int lane = tid & 63;
  const int w = tid >> 6;
  const int wr = (w >> 1) * 64;
  const int wc = (w & 1) * 64;
  const int l16 = lane & 15;
  const int lq = lane >> 4;
  const int srow = lane >> 3;
  const int scol = (lane & 7) * 8;

  for (int kk = 0; kk < KDIM; kk += 64) {
    __syncthreads();
#pragma unroll
    for (int t = 0; t < 4; t++) {
      const int r0 = w * 32 + t * 8;
      const unsigned short* g = &A[(size_t)(i0 + r0 + srow) * ASTR + kk + scol];
      __builtin_amdgcn_global_load_lds((gptr_t)(const void*)g,
                                       (lptr_t)(void*)&AsU[r0 * 64], 16, 0, 0);
    }
#pragma unroll
    for (int t = 0; t < 4; t++) {
      const int r0 = w * 32 + t * 8;
      const unsigned short* g = &B[(size_t)(j0 + r0 + srow) * BSTR + kk + scol];
      __builtin_amdgcn_global_load_lds((gptr_t)(const void*)g,
                                       (lptr_t)(void*)&BsU[r0 * 64], 16, 0, 0);
    }
    __syncthreads();

    s8v af[4][2], bf[4][2];
#pragma unroll
    for (int t = 0; t < 4; t++)
#pragma unroll
      for (int s = 0; s < 2; s++) {
        af[t][s] = *(const s8v*)&AsU[(wr + 16 * t + l16) * 64 + s * 32 + lq * 8];
        bf[t][s] = *(const s8v*)&BsU[(wc + 16 * t + l16) * 64 + s * 32 + lq * 8];
      }
#pragma unroll
    for (int s = 0; s < 2; s++)
#pragma unroll
      for (int a = 0; a < 4; a++)
#pragma unroll
        for (int b = 0; b < 4; b++)
          acc[a][b] = __builtin_amdgcn_mfma_f32_16x16x32_bf16(
              af[a][s], bf[b][s], acc[a][b], 0, 0, 0);
  }
}

// ---------------------------------------------------------------------------
// fp32 -> bf16 elementwise.
// ---------------------------------------------------------------------------
__global__ void f32_to_bf16(const float* __restrict__ in,
                            unsigned short* __restrict__ out, int n4) {
  int i = (blockIdx.x * blockDim.x + threadIdx.x);
  if (i < n4) {
    const float4 v = *(const float4*)&in[i * 4];
    ushort4 o;
    o.x = f2bf(v.x); o.y = f2bf(v.y); o.z = f2bf(v.z); o.w = f2bf(v.w);
    *(ushort4*)&out[i * 4] = o;
  }
}

// ---------------------------------------------------------------------------
// fp32 [R][C] -> bf16 [C][R] transpose+convert (32x32 LDS tiles).
// ---------------------------------------------------------------------------
__global__ void transpose_cvt(const float* __restrict__ in,
                              unsigned short* __restrict__ out, int R, int C) {
  __shared__ float t[32][33];
  const int bx = blockIdx.x;
  const int by = blockIdx.y;
  const int x = threadIdx.x & 31;
  const int y = threadIdx.x >> 5;
#pragma unroll
  for (int i = 0; i < 32; i += 8)
    t[y + i][x] = in[(size_t)(by * 32 + y + i) * C + bx * 32 + x];
  __syncthreads();
#pragma unroll
  for (int i = 0; i < 32; i += 8)
    out[(size_t)(bx * 32 + y + i) * R + by * 32 + x] = f2bf(t[x][y + i]);
}

// ---------------------------------------------------------------------------
// Projection GEMM: C[m][n] = sum_k A[m][k] * BT[n][k], bf16 in, K=1024.
// FP8OUT=true writes e4m3(16*value) for the MX qk pass.
// ---------------------------------------------------------------------------
template <int NST, bool FP8OUT>
__global__ __launch_bounds__(256, 2)
void proj_gemm(const unsigned short* __restrict__ A,
               const unsigned short* __restrict__ BT,
               void* __restrict__ Cout) {
  __shared__ __align__(16) unsigned short As[128 * 64];
  __shared__ __align__(16) unsigned short Bs[128 * 64];
  const int tid = threadIdx.x;
  const int m0 = blockIdx.y * 128;
  const int n0 = blockIdx.x * 128;

  f32x4 acc[4][4];
#pragma unroll
  for (int a = 0; a < 4; a++)
#pragma unroll
    for (int b = 0; b < 4; b++) acc[a][b] = (f32x4){0.f, 0.f, 0.f, 0.f};

  mfma_core<DD, DD, DD>(A, BT, m0, n0, tid, As, Bs, acc);

  const int lane = tid & 63;
  const int w = tid >> 6;
  const int wr = (w >> 1) * 64, wc = (w & 1) * 64;
  const int l16 = lane & 15, lq = lane >> 4;
#pragma unroll
  for (int ti = 0; ti < 4; ti++)
#pragma unroll
    for (int r = 0; r < 4; r++) {
      const int row = m0 + wr + 16 * ti + lq * 4 + r;
#pragma unroll
      for (int tj = 0; tj < 4; tj++) {
        const int col = n0 + wc + 16 * tj + l16;
        if (FP8OUT) {
          ((unsigned char*)Cout)[(size_t)row * NST + col] =
              f2e4m3(acc[ti][tj][r] * 16.f);
        } else {
          ((unsigned short*)Cout)[(size_t)row * NST + col] = f2bf(acc[ti][tj][r]);
        }
      }
    }
}

// ---------------------------------------------------------------------------
// Pass 1: P = exp(xi @ xi^T) via MX-scaled fp8 MFMA (2x bf16 rate).
// xif holds e4m3(16*xi); both MFMA scales = 2^-4 undo the pre-scaling.
// 128x128 tile, 4 waves, each 64x64 = 2x2 of mfma_scale_f32_32x32x64_f8f6f4.
// LDS: 64-B rows, 16-B chunks XOR-swizzled by (row>>1)&3.
//
// EPILOGUE IS PURE EXP+STORE with small constant-trip unrolled loops.
// R4/R5 lesson: a big epilogue body (shuffles + atomics) kept the r-loop
// rolled -> runtime index into the f32x16 acc -> whole accumulator alloca'd
// to scratch for the kernel's lifetime -> ~1.5 GB of deterministic HBM
// traffic and MfmaUtil 7%. Row sums moved to a separate row_sum kernel.
// ---------------------------------------------------------------------------
__global__ __launch_bounds__(256, 2)
void qk_fp8(const unsigned char* __restrict__ xif,  // [8192][1024] e4m3
            unsigned short* __restrict__ P) {       // [8192][8192] bf16 bits
  __shared__ __align__(16) unsigned char AsF[128 * 64];
  __shared__ __align__(16) unsigned char BsF[128 * 64];
  const int tid = threadIdx.x;
  const int lane = tid & 63;
  const int w = tid >> 6;
  const int i0 = blockIdx.y * 128;
  const int j0 = blockIdx.x * 128;

  f32x16 acc[2][2];
#pragma unroll
  for (int a = 0; a < 2; a++)
#pragma unroll
    for (int b = 0; b < 2; b++)
#pragma unroll
      for (int r = 0; r < 16; r++) acc[a][b][r] = 0.f;

  const int srow = lane >> 2;  // 0..15: row within 16-row staging group
  const int slot = lane & 3;   // 16-B chunk slot within the row
  const int kb = lane >> 5;    // frag k-block (0/1)
  const int l31 = lane & 31;

  for (int kk = 0; kk < DD; kk += 64) {
    __syncthreads();
#pragma unroll
    for (int t = 0; t < 2; t++) {
      const int r = w * 32 + t * 16 + srow;
      const int c = slot ^ ((r >> 1) & 3);  // logical chunk for this slot
      const unsigned char* ga = &xif[(size_t)(i0 + r) * DD + kk + c * 16];
      const unsigned char* gb = &xif[(size_t)(j0 + r) * DD + kk + c * 16];
      __builtin_amdgcn_global_load_lds((gptr_t)(const void*)ga,
                                       (lptr_t)(void*)&AsF[(w * 32 + t * 16) * 64],
                                       16, 0, 0);
      __builtin_amdgcn_global_load_lds((gptr_t)(const void*)gb,
                                       (lptr_t)(void*)&BsF[(w * 32 + t * 16) * 64],
                                       16, 0, 0);
    }
    __syncthreads();

    i8v af[2], bf[2];
#pragma unroll
    for (int mi = 0; mi < 2; mi++) {
      const int ar = (w >> 1) * 64 + mi * 32 + l31;
      const int sw = (ar >> 1) & 3;
      const int4 q0 = *(const int4*)&AsF[ar * 64 + ((2 * kb + 0) ^ sw) * 16];
      const int4 q1 = *(const int4*)&AsF[ar * 64 + ((2 * kb + 1) ^ sw) * 16];
      af[mi] = make_i8v(q0, q1);
    }
#pragma unroll
    for (int nj = 0; nj < 2; nj++) {
      const int br = (w & 1) * 64 + nj * 32 + l31;
      const int sw = (br >> 1) & 3;
      const int4 q0 = *(const int4*)&BsF[br * 64 + ((2 * kb + 0) ^ sw) * 16];
      const int4 q1 = *(const int4*)&BsF[br * 64 + ((2 * kb + 1) ^ sw) * 16];
      bf[nj] = make_i8v(q0, q1);
    }
#pragma unroll
    for (int mi = 0; mi < 2; mi++)
#pragma unroll
      for (int nj = 0; nj < 2; nj++)
        acc[mi][nj] = __builtin_amdgcn_mfma_scale_f32_32x32x64_f8f6f4(
            af[mi], bf[nj], acc[mi][nj], 0 /*cbsz: fp8*/, 0 /*blgp: fp8*/,
            0, SCALE_1_16, 0, SCALE_1_16);
  }

  // Epilogue: p = exp(s) -> P (bf16). Constant-trip tiny loops only.
  // C/D layout (32x32): row = (reg&3) + 8*(reg>>2) + 4*(lane>>5), col=lane&31.
  const int mbase = (w >> 1) * 64;
  const int nbase = (w & 1) * 64;
  const int rowoff = 4 * (lane >> 5);
#pragma unroll
  for (int mi = 0; mi < 2; mi++)
#pragma unroll
    for (int r4 = 0; r4 < 4; r4++)
#pragma unroll
      for (int rr = 0; rr < 4; rr++) {
        const int reg = r4 * 4 + rr;
        const int rl = mbase + mi * 32 + rr + 8 * r4 + rowoff;
        const size_t base = (size_t)(i0 + rl) * NQ + j0 + nbase + l31;
        P[base]      = f2bf(__expf(acc[mi][0][reg]));
        P[base + 32] = f2bf(__expf(acc[mi][1][reg]));
      }
}

// ---------------------------------------------------------------------------
// Row sums of P: lsum[row] = sum_j P[row][j]. One block per row, streaming
// int4 loads (8 bf16 each), wave shuffle reduce + tiny LDS combine.
// ---------------------------------------------------------------------------
__global__ __launch_bounds__(256, 4)
void row_sum(const unsigned short* __restrict__ P, float* __restrict__ lsum) {
  const int row = blockIdx.x;
  const int tid = threadIdx.x;
  const unsigned short* pr = &P[(size_t)row * NQ];
  float s = 0.f;
#pragma unroll
  for (int i = 0; i < 4; i++) {
    const int4 q = *(const int4*)&pr[(size_t)(tid + i * 256) * 8];
    // each int holds two bf16: low half -> u<<16, high half -> u&0xFFFF0000
    s += bits2f((unsigned)q.x << 16) + bits2f((unsigned)q.x & 0xFFFF0000u);
    s += bits2f((unsigned)q.y << 16) + bits2f((unsigned)q.y & 0xFFFF0000u);
    s += bits2f((unsigned)q.z << 16) + bits2f((unsigned)q.z & 0xFFFF0000u);
    s += bits2f((unsigned)q.w << 16) + bits2f((unsigned)q.w & 0xFFFF0000u);
  }
#pragma unroll
  for (int m = 32; m >= 1; m >>= 1) s += __shfl_xor(s, m);
  __shared__ float red[4];
  if ((tid & 63) == 0) red[tid >> 6] = s;
  __syncthreads();
  if (tid == 0) lsum[row] = red[0] + red[1] + red[2] + red[3];
}

// ---------------------------------------------------------------------------
// Pass 2: out = (P @ supT^T) / lsum[row], K = 8192 (bf16).
// Grid: x = i-tile (64), y = n-tile (8) -> blocks sharing a P row-slab get
// the same bid%8 (XCD) for L2 reuse of P.
// ---------------------------------------------------------------------------
__global__ __launch_bounds__(256, 2)
void pv(const unsigned short* __restrict__ P,
        const unsigned short* __restrict__ supT,
        const float* __restrict__ lsum,
        float* __restrict__ out) {
  __shared__ __align__(16) unsigned short As[128 * 64];
  __shared__ __align__(16) unsigned short Bs[128 * 64];
  const int tid = threadIdx.x;
  const int i0 = blockIdx.x * 128;
  const int n0 = blockIdx.y * 128;

  f32x4 acc[4][4];
#pragma unroll
  for (int a = 0; a < 4; a++)
#pragma unroll
    for (int b = 0; b < 4; b++) acc[a][b] = (f32x4){0.f, 0.f, 0.f, 0.f};

  mfma_core<NQ, NQ, NQ>(P, supT, i0, n0, tid, As, Bs, acc);

  const int lane = tid & 63;
  const int w = tid >> 6;
  const int wr = (w >> 1) * 64, wc = (w & 1) * 64;
  const int l16 = lane & 15, lq = lane >> 4;
#pragma unroll
  for (int ti = 0; ti < 4; ti++) {
#pragma unroll
    for (int r = 0; r < 4; r++) {
      const int row = i0 + wr + 16 * ti + lq * 4 + r;
      const float linv = 1.f / lsum[row];
#pragma unroll
      for (int tj = 0; tj < 4; tj++) {
        const int col = n0 + wc + 16 * tj + l16;
        out[(size_t)row * DD + col] = acc[ti][tj][r] * linv;
      }
    }
  }
}

// ---------------------------------------------------------------------------
// Fallback fp32 path (round-1) — only if ws_size is too small.
// ---------------------------------------------------------------------------
#define BM 64
#define BN 64
#define BK 16

__global__ __launch_bounds__(256, 4)
void gemm64(const float* __restrict__ A, const float* __restrict__ B,
            float* __restrict__ C, int M, int N, int K) {
  __shared__ __align__(16) float As[BK][BM + 4];
  __shared__ __align__(16) float Bs[BK][BN + 4];
  const int tid = threadIdx.x;
  const int tx = tid & 15;
  const int ty = tid >> 4;
  const int row0 = blockIdx.y * BM;
  const int col0 = blockIdx.x * BN;
  float acc[4][4] = {};
  for (int k0 = 0; k0 < K; k0 += BK) {
    {
      const int r = tid >> 2;
      const int c4 = (tid & 3) * 4;
      const float4 v = *(const float4*)&A[(size_t)(row0 + r) * K + k0 + c4];
      As[c4 + 0][r] = v.x; As[c4 + 1][r] = v.y;
      As[c4 + 2][r] = v.z; As[c4 + 3][r] = v.w;
    }
    {
      const int r = tid >> 4;
      const int c4 = (tid & 15) * 4;
      *(float4*)&Bs[r][c4] = *(const float4*)&B[(size_t)(k0 + r) * N + col0 + c4];
    }
    __syncthreads();
#pragma unroll
    for (int k = 0; k < BK; k++) {
      const float4 a = *(const float4*)&As[k][4 * ty];
      const float4 b = *(const float4*)&Bs[k][4 * tx];
      const float av[4] = {a.x, a.y, a.z, a.w};
      const float bv[4] = {b.x, b.y, b.z, b.w};
#pragma unroll
      for (int i = 0; i < 4; i++)
#pragma unroll
        for (int j = 0; j < 4; j++)
          acc[i][j] += av[i] * bv[j];
    }
    __syncthreads();
  }
#pragma unroll
  for (int i = 0; i < 4; i++) {
    float4 o = {acc[i][0], acc[i][1], acc[i][2], acc[i][3]};
    *(float4*)&C[(size_t)(row0 + 4 * ty + i) * N + col0 + 4 * tx] = o;
  }
}

#define IT 32
#define JT 128
#define KC 32
#define CC 128
#define NCH (DD / CC)

__global__ __launch_bounds__(256, 1)
void fused_attn(const float* __restrict__ xi, const float* __restrict__ sup,
                float* __restrict__ out) {
  __shared__ __align__(16) float XiI[KC][IT + 4];
  __shared__ __align__(16) float XiJ[KC][JT + 4];
  __shared__ __align__(16) float Ps[JT][IT + 4];
  __shared__ __align__(16) float Vs[JT][CC + 4];
  __shared__ float lsum[IT];
  const int tid = threadIdx.x;
  const int i0 = blockIdx.x * IT;
  const int ry = tid >> 5;
  const int cx = tid & 31;
  if (tid < IT) lsum[tid] = 0.f;
  float oacc[NCH][4][4];
#pragma unroll
  for (int ch = 0; ch < NCH; ch++)
#pragma unroll
    for (int i = 0; i < 4; i++)
#pragma unroll
      for (int j = 0; j < 4; j++) oacc[ch][i][j] = 0.f;
  for (int j0 = 0; j0 < NQ; j0 += JT) {
    float sacc[4][4] = {};
    for (int kc = 0; kc < DD; kc += KC) {
      __syncthreads();
      {
        const int r = tid >> 3;
        const int k4 = (tid & 7) * 4;
        const float4 v = *(const float4*)&xi[(size_t)(i0 + r) * DD + kc + k4];
        XiI[k4 + 0][r] = v.x; XiI[k4 + 1][r] = v.y;
        XiI[k4 + 2][r] = v.z; XiI[k4 + 3][r] = v.w;
      }
#pragma unroll
      for (int i = 0; i < 4; i++) {
        const int idx = tid + i * 256;
        const int r = idx >> 3;
        const int k4 = (idx & 7) * 4;
        const float4 v = *(const float4*)&xi[(size_t)(j0 + r) * DD + kc + k4];
        XiJ[k4 + 0][r] = v.x; XiJ[k4 + 1][r] = v.y;
        XiJ[k4 + 2][r] = v.z; XiJ[k4 + 3][r] = v.w;
      }
      __syncthreads();
#pragma unroll
      for (int k = 0; k < KC; k++) {
        const float4 a = *(const float4*)&XiI[k][4 * ry];
        const float4 b = *(const float4*)&XiJ[k][4 * cx];
        const float av[4] = {a.x, a.y, a.z, a.w};
        const float bv[4] = {b.x, b.y, b.z, b.w};
#pragma unroll
        for (int i = 0; i < 4; i++)
#pragma unroll
          for (int j = 0; j < 4; j++)
            sacc[i][j] += av[i] * bv[j];
      }
    }
    __syncthreads();
    float rsv[4] = {0.f, 0.f, 0.f, 0.f};
#pragma unroll
    for (int i = 0; i < 4; i++)
#pragma unroll
      for (int j = 0; j < 4; j++) {
        const float p = __expf(sacc[i][j]);
        Ps[4 * cx + j][4 * ry + i] = p;
        rsv[i] += p;
      }
#pragma unroll
    for (int m = 16; m >= 1; m >>= 1)
#pragma unroll
      for (int i = 0; i < 4; i++) rsv[i] += __shfl_xor(rsv[i], m);
    if (cx == 0) {
#pragma unroll
      for (int i = 0; i < 4; i++) lsum[4 * ry + i] += rsv[i];
    }
    for (int ch = 0; ch < NCH; ch++) {
      __syncthreads();
#pragma unroll
      for (int i = 0; i < 16; i++) {
        const int idx = tid + i * 256;
        const int r = idx >> 5;
        const int c4 = (idx & 31) * 4;
        *(float4*)&Vs[r][c4] =
            *(const float4*)&sup[(size_t)(j0 + r) * DD + ch * CC + c4];
      }
      __syncthreads();
#pragma unroll 4
      for (int jp = 0; jp < JT; jp++) {
        const float4 p = *(const float4*)&Ps[jp][4 * ry];
        const float4 v = *(const float4*)&Vs[jp][4 * cx];
        const float pvv[4] = {p.x, p.y, p.z, p.w};
        const float vv[4] = {v.x, v.y, v.z, v.w};
#pragma unroll
        for (int i = 0; i < 4; i++)
#pragma unroll
          for (int j = 0; j < 4; j++)
            oacc[ch][i][j] += pvv[i] * vv[j];
      }
    }
  }
  __syncthreads();
  float linv[4];
#pragma unroll
  for (int i = 0; i < 4; i++) linv[i] = 1.f / lsum[4 * ry + i];
#pragma unroll
  for (int ch = 0; ch < NCH; ch++)
#pragma unroll
    for (int i = 0; i < 4; i++) {
      float4 o = {oacc[ch][i][0] * linv[i], oacc[ch][i][1] * linv[i],
                  oacc[ch][i][2] * linv[i], oacc[ch][i][3] * linv[i]};
      *(float4*)&out[(size_t)(i0 + 4 * ry + i) * DD + ch * CC + 4 * cx] = o;
    }
}

// ---------------------------------------------------------------------------
// Launch. ws layout (MFMA path, NEED = 152 MB + 32 KB):
//   P    : [0, 128MB)    bf16 [8192][8192]
//   xif  : [128,136MB)   e4m3 [8192][1024] (= fp8(16*xi))
//   supT : [136,152MB)   bf16 [1024][8192]
//   lsum : [152MB,+32KB) fp32 [8192]
//   transients (consumed before P is written, alias the P region):
//     xb [0,16MB) bf16 [8192][1024];  tiT [16,18MB);  wT [18,20MB)
// NOTE: reference uses transferi for BOTH projections; transferj unused.
// ---------------------------------------------------------------------------
extern "C" void kernel_launch(void* const* d_in, const int* in_sizes, int n_in,
                              void* d_out, int out_size, void* d_ws, size_t ws_size,
                              hipStream_t stream) {
  const float* x  = (const float*)d_in[0];
  const float* wt = (const float*)d_in[1];
  const float* ti = (const float*)d_in[2];
  float* out = (float*)d_out;

  char* ws = (char*)d_ws;
  const size_t MB = 1024 * 1024;
  const size_t NEED = 152 * MB + NQ * sizeof(float);

  if (ws_size >= NEED) {
    unsigned short* P    = (unsigned short*)ws;
    unsigned char*  xif  = (unsigned char*)(ws + 128 * MB);
    unsigned short* supT = (unsigned short*)(ws + 136 * MB);
    float* lsum          = (float*)(ws + 152 * MB);
    unsigned short* xb   = (unsigned short*)ws;             // transient in P
    unsigned short* tiT  = (unsigned short*)(ws + 16 * MB); // transient in P
    unsigned short* wT   = (unsigned short*)(ws + 18 * MB); // transient in P

    const int n4 = NQ * DD / 4;
    f32_to_bf16<<<(n4 + 255) / 256, 256, 0, stream>>>(x, xb, n4);
    transpose_cvt<<<dim3(32, 32), 256, 0, stream>>>(ti, tiT, DD, DD);
    transpose_cvt<<<dim3(32, 32), 256, 0, stream>>>(wt, wT, DD, DD);

    // xif[m][n] = e4m3(16 * sum_k xb[m][k]*ti[k][n])
    proj_gemm<DD, true><<<dim3(DD / 128, NQ / 128), 256, 0, stream>>>(xb, tiT, xif);
    // supT[n][m] = bf16(sum_k W[k][n]*x[m][k])
    proj_gemm<NQ, false><<<dim3(NQ / 128, DD / 128), 256, 0, stream>>>(wT, xb, supT);

    qk_fp8<<<dim3(NQ / 128, NQ / 128), 256, 0, stream>>>(xif, P);
    row_sum<<<NQ, 256, 0, stream>>>(P, lsum);
    pv<<<dim3(NQ / 128, DD / 128), 256, 0, stream>>>(P, supT, lsum, out);
  } else {
    float* xi32  = (float*)ws;
    float* sup32 = (float*)(ws + 32 * MB);
    dim3 ggrid(DD / BN, NQ / BM);
    gemm64<<<ggrid, 256, 0, stream>>>(x, ti, xi32, NQ, DD, DD);
    gemm64<<<ggrid, 256, 0, stream>>>(x, wt, sup32, NQ, DD, DD);
    fused_attn<<<NQ / IT, 256, 0, stream>>>(xi32, sup32, out);
  }
}

// Round 7
// 369.426 us; speedup vs baseline: 2.0388x; 1.1770x over previous
//
#include <hip/hip_runtime.h>
#include <hip/hip_bf16.h>
#include <cstddef>

// Problem constants (match reference).
#define NQ 8192
#define DD 1024

typedef __attribute__((ext_vector_type(8))) short s8v;     // 8 bf16 (4 VGPR)
typedef __attribute__((ext_vector_type(8))) int i8v;       // 32 fp8 bytes (8 VGPR)
typedef __attribute__((ext_vector_type(4))) float f32x4;   // 16x16 C/D frag
typedef __attribute__((ext_vector_type(16))) float f32x16; // 32x32 C/D frag

typedef const __attribute__((address_space(1))) unsigned int* gptr_t;
typedef __attribute__((address_space(3))) unsigned int* lptr_t;

#define SCALE_1_16 0x7B7B7B7Bu  // E8M0 123 = 2^-4 in every byte

__device__ inline unsigned short f2bf(float f) {
  union { float f; unsigned u; } v; v.f = f;
  unsigned r = (v.u + 0x7FFFu + ((v.u >> 16) & 1u)) >> 16;  // RNE
  return (unsigned short)r;
}
__device__ inline float bf2f(unsigned short u) {
  union { unsigned u; float f; } v; v.u = ((unsigned)u) << 16;
  return v.f;
}
__device__ inline float bits2f(unsigned u) {
  union { unsigned u; float f; } v; v.u = u;
  return v.f;
}

// f32 -> OCP e4m3 bits, RNE, clamp to +-448.
__device__ inline unsigned char f2e4m3(float x) {
  union { float f; unsigned u; } v; v.f = x;
  const unsigned s = (v.u >> 31) << 7;
  unsigned au = v.u & 0x7FFFFFFFu;
  if (au > 0x43E00000u) au = 0x43E00000u;  // clamp |x| to 448.0
  if (au >= 0x3C800000u) {                 // |x| >= 2^-6: e4m3 normal
    const unsigned rounded = au + 0x7FFFFu + ((au >> 20) & 1u);  // RNE @ 3 mant
    const unsigned e8 = ((rounded >> 23) & 0xFF) - 120u;         // -127+7
    const unsigned m8 = (rounded >> 20) & 7u;
    return (unsigned char)(s | (e8 << 3) | m8);
  } else {                                 // subnormal
    union { unsigned u; float f; } a; a.u = au;
    const unsigned q = (unsigned)rintf(a.f * 512.0f);  // 0..8
    return (unsigned char)(s | q);
  }
}

// Register-only combine of two 16-B LDS loads into one fp8 MFMA operand.
__device__ inline i8v make_i8v(int4 a, int4 b) {
  i8v v;
  v[0] = a.x; v[1] = a.y; v[2] = a.z; v[3] = a.w;
  v[4] = b.x; v[5] = b.y; v[6] = b.z; v[7] = b.w;
  return v;
}

// ---------------------------------------------------------------------------
// m97-style bf16 MFMA main loop: C(128x128) += A(128xK) @ B(128xK)^T.
// BK=64, global_load_lds dwordx4 staging, 4 waves, each 64x64 via 4x4 of
// 16x16x32 bf16 MFMA. Used by proj_gemm and pv.
//
// LDS rows are 64 shorts = 128 B = exactly 32 banks. R6 counters showed
// 5e7 bank conflicts (~12 extra cyc per ds_read_b128): un-swizzled, all 16
// l16-lanes of an lq-group read the same 16-B chunk (8-way/beat). Fix:
// XOR-swizzle 16-B chunks by row&7. Staging keeps the mandated wave-uniform
// base + lane*16 LDS dest; only the per-lane GLOBAL source column is
// permuted (same 128-B segment -> coalescing intact). Frag reads use
// chunk = (4s+lq) ^ (l16&7): per 8-lane beat, 8 distinct chunks = 32 banks.
// ---------------------------------------------------------------------------
template <int KDIM, int ASTR, int BSTR>
__device__ inline void mfma_core(const unsigned short* __restrict__ A,
                                 const unsigned short* __restrict__ B,
                                 int i0, int j0, int tid,
                                 unsigned short* AsU, unsigned short* BsU,
                                 f32x4 (&acc)[4][4]) {
  const int lane = tid & 63;
  const int w = tid >> 6;
  const int wr = (w >> 1) * 64;
  const int wc = (w & 1) * 64;
  const int l16 = lane & 15;
  const int lq = lane >> 4;
  const int srow = lane >> 3;                          // 0..7
  const int scol = (((lane & 7) ^ (srow & 7)) * 8);    // swizzled 16-B chunk

  for (int kk = 0; kk < KDIM; kk += 64) {
    __syncthreads();
#pragma unroll
    for (int t = 0; t < 4; t++) {
      const int r0 = w * 32 + t * 8;
      const unsigned short* g = &A[(size_t)(i0 + r0 + srow) * ASTR + kk + scol];
      __builtin_amdgcn_global_load_lds((gptr_t)(const void*)g,
                                       (lptr_t)(void*)&AsU[r0 * 64], 16, 0, 0);
    }
#pragma unroll
    for (int t = 0; t < 4; t++) {
      const int r0 = w * 32 + t * 8;
      const unsigned short* g = &B[(size_t)(j0 + r0 + srow) * BSTR + kk + scol];
      __builtin_amdgcn_global_load_lds((gptr_t)(const void*)g,
                                       (lptr_t)(void*)&BsU[r0 * 64], 16, 0, 0);
    }
    __syncthreads();

    const int h = l16 & 7;
    s8v af[4][2], bf[4][2];
#pragma unroll
    for (int t = 0; t < 4; t++)
#pragma unroll
      for (int s = 0; s < 2; s++) {
        const int ch = ((s * 4 + lq) ^ h) * 8;  // swizzled chunk offset
        af[t][s] = *(const s8v*)&AsU[(wr + 16 * t + l16) * 64 + ch];
        bf[t][s] = *(const s8v*)&BsU[(wc + 16 * t + l16) * 64 + ch];
      }
#pragma unroll
    for (int s = 0; s < 2; s++)
#pragma unroll
      for (int a = 0; a < 4; a++)
#pragma unroll
        for (int b = 0; b < 4; b++)
          acc[a][b] = __builtin_amdgcn_mfma_f32_16x16x32_bf16(
              af[a][s], bf[b][s], acc[a][b], 0, 0, 0);
  }
}

// ---------------------------------------------------------------------------
// fp32 -> bf16 elementwise.
// ---------------------------------------------------------------------------
__global__ void f32_to_bf16(const float* __restrict__ in,
                            unsigned short* __restrict__ out, int n4) {
  int i = (blockIdx.x * blockDim.x + threadIdx.x);
  if (i < n4) {
    const float4 v = *(const float4*)&in[i * 4];
    ushort4 o;
    o.x = f2bf(v.x); o.y = f2bf(v.y); o.z = f2bf(v.z); o.w = f2bf(v.w);
    *(ushort4*)&out[i * 4] = o;
  }
}

// ---------------------------------------------------------------------------
// fp32 [R][C] -> bf16 [C][R] transpose+convert (32x32 LDS tiles).
// ---------------------------------------------------------------------------
__global__ void transpose_cvt(const float* __restrict__ in,
                              unsigned short* __restrict__ out, int R, int C) {
  __shared__ float t[32][33];
  const int bx = blockIdx.x;
  const int by = blockIdx.y;
  const int x = threadIdx.x & 31;
  const int y = threadIdx.x >> 5;
#pragma unroll
  for (int i = 0; i < 32; i += 8)
    t[y + i][x] = in[(size_t)(by * 32 + y + i) * C + bx * 32 + x];
  __syncthreads();
#pragma unroll
  for (int i = 0; i < 32; i += 8)
    out[(size_t)(bx * 32 + y + i) * R + by * 32 + x] = f2bf(t[x][y + i]);
}

// ---------------------------------------------------------------------------
// Projection GEMM: C[m][n] = sum_k A[m][k] * BT[n][k], bf16 in, K=1024.
// FP8OUT=true writes e4m3(16*value) for the MX qk pass.
// ---------------------------------------------------------------------------
template <int NST, bool FP8OUT>
__global__ __launch_bounds__(256, 2)
void proj_gemm(const unsigned short* __restrict__ A,
               const unsigned short* __restrict__ BT,
               void* __restrict__ Cout) {
  __shared__ __align__(16) unsigned short As[128 * 64];
  __shared__ __align__(16) unsigned short Bs[128 * 64];
  const int tid = threadIdx.x;
  const int m0 = blockIdx.y * 128;
  const int n0 = blockIdx.x * 128;

  f32x4 acc[4][4];
#pragma unroll
  for (int a = 0; a < 4; a++)
#pragma unroll
    for (int b = 0; b < 4; b++) acc[a][b] = (f32x4){0.f, 0.f, 0.f, 0.f};

  mfma_core<DD, DD, DD>(A, BT, m0, n0, tid, As, Bs, acc);

  const int lane = tid & 63;
  const int w = tid >> 6;
  const int wr = (w >> 1) * 64, wc = (w & 1) * 64;
  const int l16 = lane & 15, lq = lane >> 4;
#pragma unroll
  for (int ti = 0; ti < 4; ti++)
#pragma unroll
    for (int r = 0; r < 4; r++) {
      const int row = m0 + wr + 16 * ti + lq * 4 + r;
#pragma unroll
      for (int tj = 0; tj < 4; tj++) {
        const int col = n0 + wc + 16 * tj + l16;
        if (FP8OUT) {
          ((unsigned char*)Cout)[(size_t)row * NST + col] =
              f2e4m3(acc[ti][tj][r] * 16.f);
        } else {
          ((unsigned short*)Cout)[(size_t)row * NST + col] = f2bf(acc[ti][tj][r]);
        }
      }
    }
}

// ---------------------------------------------------------------------------
// Pass 1: P = exp(xi @ xi^T) via MX-scaled fp8 MFMA (2x bf16 rate).
// xif holds e4m3(16*xi); both MFMA scales = 2^-4 undo the pre-scaling.
// 128x128 tile, 4 waves, each 64x64 = 2x2 of mfma_scale_f32_32x32x64_f8f6f4.
// LDS: 64-B rows, 16-B chunks XOR-swizzled by (row>>1)&3.
// Epilogue: pure exp+store, constant-trip loops only (R5 scratch lesson).
// ---------------------------------------------------------------------------
__global__ __launch_bounds__(256, 2)
void qk_fp8(const unsigned char* __restrict__ xif,  // [8192][1024] e4m3
            unsigned short* __restrict__ P) {       // [8192][8192] bf16 bits
  __shared__ __align__(16) unsigned char AsF[128 * 64];
  __shared__ __align__(16) unsigned char BsF[128 * 64];
  const int tid = threadIdx.x;
  const int lane = tid & 63;
  const int w = tid >> 6;
  const int i0 = blockIdx.y * 128;
  const int j0 = blockIdx.x * 128;

  f32x16 acc[2][2];
#pragma unroll
  for (int a = 0; a < 2; a++)
#pragma unroll
    for (int b = 0; b < 2; b++)
#pragma unroll
      for (int r = 0; r < 16; r++) acc[a][b][r] = 0.f;

  const int srow = lane >> 2;  // 0..15: row within 16-row staging group
  const int slot = lane & 3;   // 16-B chunk slot within the row
  const int kb = lane >> 5;    // frag k-block (0/1)
  const int l31 = lane & 31;

  for (int kk = 0; kk < DD; kk += 64) {
    __syncthreads();
#pragma unroll
    for (int t = 0; t < 2; t++) {
      const int r = w * 32 + t * 16 + srow;
      const int c = slot ^ ((r >> 1) & 3);  // logical chunk for this slot
      const unsigned char* ga = &xif[(size_t)(i0 + r) * DD + kk + c * 16];
      const unsigned char* gb = &xif[(size_t)(j0 + r) * DD + kk + c * 16];
      __builtin_amdgcn_global_load_lds((gptr_t)(const void*)ga,
                                       (lptr_t)(void*)&AsF[(w * 32 + t * 16) * 64],
                                       16, 0, 0);
      __builtin_amdgcn_global_load_lds((gptr_t)(const void*)gb,
                                       (lptr_t)(void*)&BsF[(w * 32 + t * 16) * 64],
                                       16, 0, 0);
    }
    __syncthreads();

    i8v af[2], bf[2];
#pragma unroll
    for (int mi = 0; mi < 2; mi++) {
      const int ar = (w >> 1) * 64 + mi * 32 + l31;
      const int sw = (ar >> 1) & 3;
      const int4 q0 = *(const int4*)&AsF[ar * 64 + ((2 * kb + 0) ^ sw) * 16];
      const int4 q1 = *(const int4*)&AsF[ar * 64 + ((2 * kb + 1) ^ sw) * 16];
      af[mi] = make_i8v(q0, q1);
    }
#pragma unroll
    for (int nj = 0; nj < 2; nj++) {
      const int br = (w & 1) * 64 + nj * 32 + l31;
      const int sw = (br >> 1) & 3;
      const int4 q0 = *(const int4*)&BsF[br * 64 + ((2 * kb + 0) ^ sw) * 16];
      const int4 q1 = *(const int4*)&BsF[br * 64 + ((2 * kb + 1) ^ sw) * 16];
      bf[nj] = make_i8v(q0, q1);
    }
#pragma unroll
    for (int mi = 0; mi < 2; mi++)
#pragma unroll
      for (int nj = 0; nj < 2; nj++)
        acc[mi][nj] = __builtin_amdgcn_mfma_scale_f32_32x32x64_f8f6f4(
            af[mi], bf[nj], acc[mi][nj], 0 /*cbsz: fp8*/, 0 /*blgp: fp8*/,
            0, SCALE_1_16, 0, SCALE_1_16);
  }

  // Epilogue: p = exp(s) -> P (bf16). Constant-trip tiny loops only.
  const int mbase = (w >> 1) * 64;
  const int nbase = (w & 1) * 64;
  const int rowoff = 4 * (lane >> 5);
#pragma unroll
  for (int mi = 0; mi < 2; mi++)
#pragma unroll
    for (int r4 = 0; r4 < 4; r4++)
#pragma unroll
      for (int rr = 0; rr < 4; rr++) {
        const int reg = r4 * 4 + rr;
        const int rl = mbase + mi * 32 + rr + 8 * r4 + rowoff;
        const size_t base = (size_t)(i0 + rl) * NQ + j0 + nbase + l31;
        P[base]      = f2bf(__expf(acc[mi][0][reg]));
        P[base + 32] = f2bf(__expf(acc[mi][1][reg]));
      }
}

// ---------------------------------------------------------------------------
// Row sums of P: lsum[row] = sum_j P[row][j].
// ---------------------------------------------------------------------------
__global__ __launch_bounds__(256, 4)
void row_sum(const unsigned short* __restrict__ P, float* __restrict__ lsum) {
  const int row = blockIdx.x;
  const int tid = threadIdx.x;
  const unsigned short* pr = &P[(size_t)row * NQ];
  float s = 0.f;
#pragma unroll
  for (int i = 0; i < 4; i++) {
    const int4 q = *(const int4*)&pr[(size_t)(tid + i * 256) * 8];
    s += bits2f((unsigned)q.x << 16) + bits2f((unsigned)q.x & 0xFFFF0000u);
    s += bits2f((unsigned)q.y << 16) + bits2f((unsigned)q.y & 0xFFFF0000u);
    s += bits2f((unsigned)q.z << 16) + bits2f((unsigned)q.z & 0xFFFF0000u);
    s += bits2f((unsigned)q.w << 16) + bits2f((unsigned)q.w & 0xFFFF0000u);
  }
#pragma unroll
  for (int m = 32; m >= 1; m >>= 1) s += __shfl_xor(s, m);
  __shared__ float red[4];
  if ((tid & 63) == 0) red[tid >> 6] = s;
  __syncthreads();
  if (tid == 0) lsum[row] = red[0] + red[1] + red[2] + red[3];
}

// ---------------------------------------------------------------------------
// Pass 2: out = (P @ supT^T) / lsum[row], K = 8192 (bf16).
// Grid: x = i-tile (64), y = n-tile (8) -> blocks sharing a P row-slab get
// the same bid%8 (XCD) for L2 reuse of P.
// ---------------------------------------------------------------------------
__global__ __launch_bounds__(256, 2)
void pv(const unsigned short* __restrict__ P,
        const unsigned short* __restrict__ supT,
        const float* __restrict__ lsum,
        float* __restrict__ out) {
  __shared__ __align__(16) unsigned short As[128 * 64];
  __shared__ __align__(16) unsigned short Bs[128 * 64];
  const int tid = threadIdx.x;
  const int i0 = blockIdx.x * 128;
  const int n0 = blockIdx.y * 128;

  f32x4 acc[4][4];
#pragma unroll
  for (int a = 0; a < 4; a++)
#pragma unroll
    for (int b = 0; b < 4; b++) acc[a][b] = (f32x4){0.f, 0.f, 0.f, 0.f};

  mfma_core<NQ, NQ, NQ>(P, supT, i0, n0, tid, As, Bs, acc);

  const int lane = tid & 63;
  const int w = tid >> 6;
  const int wr = (w >> 1) * 64, wc = (w & 1) * 64;
  const int l16 = lane & 15, lq = lane >> 4;
#pragma unroll
  for (int ti = 0; ti < 4; ti++) {
#pragma unroll
    for (int r = 0; r < 4; r++) {
      const int row = i0 + wr + 16 * ti + lq * 4 + r;
      const float linv = 1.f / lsum[row];
#pragma unroll
      for (int tj = 0; tj < 4; tj++) {
        const int col = n0 + wc + 16 * tj + l16;
        out[(size_t)row * DD + col] = acc[ti][tj][r] * linv;
      }
    }
  }
}

// ---------------------------------------------------------------------------
// Fallback fp32 path (round-1) — only if ws_size is too small.
// ---------------------------------------------------------------------------
#define BM 64
#define BN 64
#define BK 16

__global__ __launch_bounds__(256, 4)
void gemm64(const float* __restrict__ A, const float* __restrict__ B,
            float* __restrict__ C, int M, int N, int K) {
  __shared__ __align__(16) float As[BK][BM + 4];
  __shared__ __align__(16) float Bs[BK][BN + 4];
  const int tid = threadIdx.x;
  const int tx = tid & 15;
  const int ty = tid >> 4;
  const int row0 = blockIdx.y * BM;
  const int col0 = blockIdx.x * BN;
  float acc[4][4] = {};
  for (int k0 = 0; k0 < K; k0 += BK) {
    {
      const int r = tid >> 2;
      const int c4 = (tid & 3) * 4;
      const float4 v = *(const float4*)&A[(size_t)(row0 + r) * K + k0 + c4];
      As[c4 + 0][r] = v.x; As[c4 + 1][r] = v.y;
      As[c4 + 2][r] = v.z; As[c4 + 3][r] = v.w;
    }
    {
      const int r = tid >> 4;
      const int c4 = (tid & 15) * 4;
      *(float4*)&Bs[r][c4] = *(const float4*)&B[(size_t)(k0 + r) * N + col0 + c4];
    }
    __syncthreads();
#pragma unroll
    for (int k = 0; k < BK; k++) {
      const float4 a = *(const float4*)&As[k][4 * ty];
      const float4 b = *(const float4*)&Bs[k][4 * tx];
      const float av[4] = {a.x, a.y, a.z, a.w};
      const float bv[4] = {b.x, b.y, b.z, b.w};
#pragma unroll
      for (int i = 0; i < 4; i++)
#pragma unroll
        for (int j = 0; j < 4; j++)
          acc[i][j] += av[i] * bv[j];
    }
    __syncthreads();
  }
#pragma unroll
  for (int i = 0; i < 4; i++) {
    float4 o = {acc[i][0], acc[i][1], acc[i][2], acc[i][3]};
    *(float4*)&C[(size_t)(row0 + 4 * ty + i) * N + col0 + 4 * tx] = o;
  }
}

#define IT 32
#define JT 128
#define KC 32
#define CC 128
#define NCH (DD / CC)

__global__ __launch_bounds__(256, 1)
void fused_attn(const float* __restrict__ xi, const float* __restrict__ sup,
                float* __restrict__ out) {
  __shared__ __align__(16) float XiI[KC][IT + 4];
  __shared__ __align__(16) float XiJ[KC][JT + 4];
  __shared__ __align__(16) float Ps[JT][IT + 4];
  __shared__ __align__(16) float Vs[JT][CC + 4];
  __shared__ float lsum[IT];
  const int tid = threadIdx.x;
  const int i0 = blockIdx.x * IT;
  const int ry = tid >> 5;
  const int cx = tid & 31;
  if (tid < IT) lsum[tid] = 0.f;
  float oacc[NCH][4][4];
#pragma unroll
  for (int ch = 0; ch < NCH; ch++)
#pragma unroll
    for (int i = 0; i < 4; i++)
#pragma unroll
      for (int j = 0; j < 4; j++) oacc[ch][i][j] = 0.f;
  for (int j0 = 0; j0 < NQ; j0 += JT) {
    float sacc[4][4] = {};
    for (int kc = 0; kc < DD; kc += KC) {
      __syncthreads();
      {
        const int r = tid >> 3;
        const int k4 = (tid & 7) * 4;
        const float4 v = *(const float4*)&xi[(size_t)(i0 + r) * DD + kc + k4];
        XiI[k4 + 0][r] = v.x; XiI[k4 + 1][r] = v.y;
        XiI[k4 + 2][r] = v.z; XiI[k4 + 3][r] = v.w;
      }
#pragma unroll
      for (int i = 0; i < 4; i++) {
        const int idx = tid + i * 256;
        const int r = idx >> 3;
        const int k4 = (idx & 7) * 4;
        const float4 v = *(const float4*)&xi[(size_t)(j0 + r) * DD + kc + k4];
        XiJ[k4 + 0][r] = v.x; XiJ[k4 + 1][r] = v.y;
        XiJ[k4 + 2][r] = v.z; XiJ[k4 + 3][r] = v.w;
      }
      __syncthreads();
#pragma unroll
      for (int k = 0; k < KC; k++) {
        const float4 a = *(const float4*)&XiI[k][4 * ry];
        const float4 b = *(const float4*)&XiJ[k][4 * cx];
        const float av[4] = {a.x, a.y, a.z, a.w};
        const float bv[4] = {b.x, b.y, b.z, b.w};
#pragma unroll
        for (int i = 0; i < 4; i++)
#pragma unroll
          for (int j = 0; j < 4; j++)
            sacc[i][j] += av[i] * bv[j];
      }
    }
    __syncthreads();
    float rsv[4] = {0.f, 0.f, 0.f, 0.f};
#pragma unroll
    for (int i = 0; i < 4; i++)
#pragma unroll
      for (int j = 0; j < 4; j++) {
        const float p = __expf(sacc[i][j]);
        Ps[4 * cx + j][4 * ry + i] = p;
        rsv[i] += p;
      }
#pragma unroll
    for (int m = 16; m >= 1; m >>= 1)
#pragma unroll
      for (int i = 0; i < 4; i++) rsv[i] += __shfl_xor(rsv[i], m);
    if (cx == 0) {
#pragma unroll
      for (int i = 0; i < 4; i++) lsum[4 * ry + i] += rsv[i];
    }
    for (int ch = 0; ch < NCH; ch++) {
      __syncthreads();
#pragma unroll
      for (int i = 0; i < 16; i++) {
        const int idx = tid + i * 256;
        const int r = idx >> 5;
        const int c4 = (idx & 31) * 4;
        *(float4*)&Vs[r][c4] =
            *(const float4*)&sup[(size_t)(j0 + r) * DD + ch * CC + c4];
      }
      __syncthreads();
#pragma unroll 4
      for (int jp = 0; jp < JT; jp++) {
        const float4 p = *(const float4*)&Ps[jp][4 * ry];
        const float4 v = *(const float4*)&Vs[jp][4 * cx];
        const float pvv[4] = {p.x, p.y, p.z, p.w};
        const float vv[4] = {v.x, v.y, v.z, v.w};
#pragma unroll
        for (int i = 0; i < 4; i++)
#pragma unroll
          for (int j = 0; j < 4; j++)
            oacc[ch][i][j] += pvv[i] * vv[j];
      }
    }
  }
  __syncthreads();
  float linv[4];
#pragma unroll
  for (int i = 0; i < 4; i++) linv[i] = 1.f / lsum[4 * ry + i];
#pragma unroll
  for (int ch = 0; ch < NCH; ch++)
#pragma unroll
    for (int i = 0; i < 4; i++) {
      float4 o = {oacc[ch][i][0] * linv[i], oacc[ch][i][1] * linv[i],
                  oacc[ch][i][2] * linv[i], oacc[ch][i][3] * linv[i]};
      *(float4*)&out[(size_t)(i0 + 4 * ry + i) * DD + ch * CC + 4 * cx] = o;
    }
}

// ---------------------------------------------------------------------------
// Launch. ws layout (MFMA path, NEED = 152 MB + 32 KB):
//   P    : [0, 128MB)    bf16 [8192][8192]
//   xif  : [128,136MB)   e4m3 [8192][1024] (= fp8(16*xi))
//   supT : [136,152MB)   bf16 [1024][8192]
//   lsum : [152MB,+32KB) fp32 [8192]
//   transients (consumed before P is written, alias the P region):
//     xb [0,16MB) bf16 [8192][1024];  tiT [16,18MB);  wT [18,20MB)
// NOTE: reference uses transferi for BOTH projections; transferj unused.
// ---------------------------------------------------------------------------
extern "C" void kernel_launch(void* const* d_in, const int* in_sizes, int n_in,
                              void* d_out, int out_size, void* d_ws, size_t ws_size,
                              hipStream_t stream) {
  const float* x  = (const float*)d_in[0];
  const float* wt = (const float*)d_in[1];
  const float* ti = (const float*)d_in[2];
  float* out = (float*)d_out;

  char* ws = (char*)d_ws;
  const size_t MB = 1024 * 1024;
  const size_t NEED = 152 * MB + NQ * sizeof(float);

  if (ws_size >= NEED) {
    unsigned short* P    = (unsigned short*)ws;
    unsigned char*  xif  = (unsigned char*)(ws + 128 * MB);
    unsigned short* supT = (unsigned short*)(ws + 136 * MB);
    float* lsum          = (float*)(ws + 152 * MB);
    unsigned short* xb   = (unsigned short*)ws;             // transient in P
    unsigned short* tiT  = (unsigned short*)(ws + 16 * MB); // transient in P
    unsigned short* wT   = (unsigned short*)(ws + 18 * MB); // transient in P

    const int n4 = NQ * DD / 4;
    f32_to_bf16<<<(n4 + 255) / 256, 256, 0, stream>>>(x, xb, n4);
    transpose_cvt<<<dim3(32, 32), 256, 0, stream>>>(ti, tiT, DD, DD);
    transpose_cvt<<<dim3(32, 32), 256, 0, stream>>>(wt, wT, DD, DD);

    // xif[m][n] = e4m3(16 * sum_k xb[m][k]*ti[k][n])
    proj_gemm<DD, true><<<dim3(DD / 128, NQ / 128), 256, 0, stream>>>(xb, tiT, xif);
    // supT[n][m] = bf16(sum_k W[k][n]*x[m][k])
    proj_gemm<NQ, false><<<dim3(NQ / 128, DD / 128), 256, 0, stream>>>(wT, xb, supT);

    qk_fp8<<<dim3(NQ / 128, NQ / 128), 256, 0, stream>>>(xif, P);
    row_sum<<<NQ, 256, 0, stream>>>(P, lsum);
    pv<<<dim3(NQ / 128, DD / 128), 256, 0, stream>>>(P, supT, lsum, out);
  } else {
    float* xi32  = (float*)ws;
    float* sup32 = (float*)(ws + 32 * MB);
    dim3 ggrid(DD / BN, NQ / BM);
    gemm64<<<ggrid, 256, 0, stream>>>(x, ti, xi32, NQ, DD, DD);
    gemm64<<<ggrid, 256, 0, stream>>>(x, wt, sup32, NQ, DD, DD);
    fused_attn<<<NQ / IT, 256, 0, stream>>>(xi32, sup32, out);
  }
}